// Round 1
// baseline (552.241 us; speedup 1.0000x reference)
//
#include <hip/hip_runtime.h>
#include <math.h>

#define BATCH 128
#define TLEN 512
#define XF 266
#define HID 192
#define NC 250

typedef __attribute__((ext_vector_type(8))) short short8;
typedef __attribute__((ext_vector_type(4))) float float4v;

#define NL2E  -1.4426950408889634f
#define NL2E2 -2.8853900817779268f

// fp32 -> bf16 (RNE)
__device__ __forceinline__ unsigned short f2bf(float f) {
  unsigned u = __float_as_uint(f);
  u += 0x7FFF + ((u >> 16) & 1);
  return (unsigned short)(u >> 16);
}
__device__ __forceinline__ float bf2f(unsigned short s) {
  return __uint_as_float(((unsigned)s) << 16);
}

// LDS-only barrier: does NOT drain vmcnt.
__device__ __forceinline__ void lds_barrier() {
  asm volatile("s_waitcnt lgkmcnt(0)\n\ts_barrier" ::: "memory");
}

// ---------------- K1: feature prep --------------------------------------
// Hands: [tile8][t][m16][HS]  (HS=64 hoist-mode, zeros 42..63; HS=48 fallback)
// Arms:  [tile4][t][m32][8]   (6 real + 2 zero)

__device__ __forceinline__ void norm_hand(const float* __restrict__ xp,
                                          unsigned short* __restrict__ fp,
                                          int p0, int refp, int hs) {
  float rx = xp[2 * refp], ry = xp[2 * refp + 1];
  float px[21], py[21];
  float minx = 1e30f, maxx = -1e30f, miny = 1e30f, maxy = -1e30f;
#pragma unroll
  for (int i = 0; i < 21; ++i) {
    float ax = xp[2 * (p0 + i)] - rx;
    float ay = xp[2 * (p0 + i) + 1] - ry;
    px[i] = ax; py[i] = ay;
    minx = fminf(minx, ax); maxx = fmaxf(maxx, ax);
    miny = fminf(miny, ay); maxy = fmaxf(maxy, ay);
  }
  float s = fmaxf(maxx - minx, maxy - miny);
  if (s == 0.f) s = 1.f;
  float inv = 1.f / s;
#pragma unroll
  for (int i = 0; i < 21; ++i) {
    fp[2 * i] = f2bf(px[i] * inv);
    fp[2 * i + 1] = f2bf(py[i] * inv);
  }
  for (int i = 42; i < hs; ++i) fp[i] = 0;
}

__device__ __forceinline__ void norm_arm(const float* __restrict__ xp,
                                         unsigned short* __restrict__ fp,
                                         int a, int b, int c) {
  float rx = xp[0], ry = xp[1];
  float x0 = xp[2 * a] - rx, y0 = xp[2 * a + 1] - ry;
  float x1 = xp[2 * b] - rx, y1 = xp[2 * b + 1] - ry;
  float x2 = xp[2 * c] - rx, y2 = xp[2 * c + 1] - ry;
  float w = fmaxf(fmaxf(x0, x1), x2) - fminf(fminf(x0, x1), x2);
  float h = fmaxf(fmaxf(y0, y1), y2) - fminf(fminf(y0, y1), y2);
  float s = fmaxf(w, h);
  if (s == 0.f) s = 1.f;
  float inv = 1.f / s;
  fp[0] = f2bf(x0 * inv); fp[1] = f2bf(y0 * inv);
  fp[2] = f2bf(x1 * inv); fp[3] = f2bf(y1 * inv);
  fp[4] = f2bf(x2 * inv); fp[5] = f2bf(y2 * inv);
  fp[6] = 0; fp[7] = 0;
}

__global__ __launch_bounds__(256) void prep_kernel(
    const float* __restrict__ x,
    unsigned short* __restrict__ fHR, unsigned short* __restrict__ fHL,
    unsigned short* __restrict__ fAR, unsigned short* __restrict__ fAL,
    int hs) {
  int idx = blockIdx.x * 256 + threadIdx.x;
  if (idx >= BATCH * TLEN) return;
  int b = idx >> 9, t = idx & 511;
  const float* xp = x + (size_t)idx * XF;
  size_t hoff = (((size_t)(b >> 4) * TLEN + t) * 16 + (b & 15)) * hs;
  size_t aoff = (((size_t)(b >> 5) * TLEN + t) * 32 + (b & 31)) * 8;
  norm_hand(xp, fHR + hoff, 112, 10, hs);  // right hand, ref pt 10
  norm_hand(xp, fHL + hoff, 91, 9, hs);    // left hand, ref pt 9
  norm_arm (xp, fAR + aoff, 6, 8, 10);     // right arm
  norm_arm (xp, fAL + aoff, 5, 7, 9);      // left arm
}

// ---------------- K1b: weight packing -----------------------------------
// All gate weights pre-scaled by -log2(e) (gates i,f,o) / -2*log2(e) (gate g)
// so the recurrence uses bare v_exp_f32 (exp2) with no per-element mul.
// mode 1 (hoist): btA = Wih^T [256][64] (k<42), btH = Whh^T [256][64]
// mode 0 (fallback): btA = [256][128] = [wih42|0|whh64]
// arms (both): btArm [128][64] = [wih6|0|whh32]

__global__ __launch_bounds__(256) void pack_kernel(
    int mode,
    const float* __restrict__ wi_rh, const float* __restrict__ wh_rh,
    const float* __restrict__ wi_ra, const float* __restrict__ wh_ra,
    const float* __restrict__ wi_lh, const float* __restrict__ wh_lh,
    const float* __restrict__ wi_la, const float* __restrict__ wh_la,
    unsigned short* __restrict__ btA_r, unsigned short* __restrict__ btA_l,
    unsigned short* __restrict__ btH_r, unsigned short* __restrict__ btH_l,
    unsigned short* __restrict__ btArm_r, unsigned short* __restrict__ btArm_l) {
  int blk = blockIdx.x, tid = threadIdx.x;
  if (blk < 2) {
    const float* wi = blk ? wi_lh : wi_rh;
    const float* wh = blk ? wh_lh : wh_rh;
    unsigned short* dst = blk ? btA_l : btA_r;
    if (mode) {
      for (int i = tid; i < 256 * 64; i += 256) {
        int g = i >> 6, k = i & 63;
        float s = ((g >> 6) == 2) ? NL2E2 : NL2E;
        dst[i] = f2bf(k < 42 ? wi[g * 42 + k] * s : 0.f);
      }
    } else {
      for (int i = tid; i < 256 * 128; i += 256) {
        int g = i >> 7, k = i & 127;
        float s = ((g >> 6) == 2) ? NL2E2 : NL2E;
        float v = (k < 42) ? wi[g * 42 + k] : (k < 64 ? 0.f : wh[g * 64 + (k - 64)]);
        dst[i] = f2bf(v * s);
      }
    }
  } else if (blk < 4) {
    if (mode) {
      const float* wh = (blk == 3) ? wh_lh : wh_rh;
      unsigned short* dst = (blk == 3) ? btH_l : btH_r;
      for (int i = tid; i < 256 * 64; i += 256) {
        int g = i >> 6;
        float s = ((g >> 6) == 2) ? NL2E2 : NL2E;
        dst[i] = f2bf(wh[i] * s);
      }
    }
  } else {
    const float* wi = (blk == 5) ? wi_la : wi_ra;
    const float* wh = (blk == 5) ? wh_la : wh_ra;
    unsigned short* dst = (blk == 5) ? btArm_l : btArm_r;
    for (int i = tid; i < 128 * 64; i += 256) {
      int g = i >> 6, k = i & 63;
      float s = ((g >> 5) == 2) ? NL2E2 : NL2E;
      float v = (k < 6) ? wi[g * 6 + k] : (k < 32 ? 0.f : wh[g * 32 + (k - 32)]);
      dst[i] = f2bf(v * s);
    }
  }
}

// ---------------- K1c: input-projection pre-GEMM (hoist mode) ------------
// pre[(tile*512+t)*4096 + jg*1024 + n*64 + quad*16 + q*4 + r] (bf16), with
// scaled bias folded (btA already scaled in pack). 256 blocks.

__global__ __launch_bounds__(256, 1) void pregemm_kernel(
    const unsigned short* __restrict__ f64R, const unsigned short* __restrict__ f64L,
    const unsigned short* __restrict__ btiR, const unsigned short* __restrict__ btiL,
    const float* __restrict__ biR, const float* __restrict__ bhR,
    const float* __restrict__ biL, const float* __restrict__ bhL,
    unsigned short* __restrict__ preR, unsigned short* __restrict__ preL) {
  int bx = blockIdx.x;
  int lr = bx >> 7, tile = (bx >> 4) & 7, tc = bx & 15;
  const unsigned short* f64 = lr ? f64L : f64R;
  const unsigned short* bti = lr ? btiL : btiR;
  const float* bi = lr ? biL : biR;
  const float* bh = lr ? bhL : bhR;
  unsigned short* pre = lr ? preL : preR;
  int tid = threadIdx.x, lane = tid & 63;
  int q = tid >> 6, n = lane & 15, quad = lane >> 4;
  float sq = (q == 2) ? NL2E2 : NL2E;

  short8 Vb[4][2];
  float bias[4];
#pragma unroll
  for (int jg = 0; jg < 4; ++jg) {
    int g = q * 64 + jg * 16 + n;
    bias[jg] = (bi[g] + bh[g]) * sq;
#pragma unroll
    for (int c = 0; c < 2; ++c)
      Vb[jg][c] = *(const short8*)(bti + (size_t)g * 64 + c * 32 + quad * 8);
  }

  for (int i = 0; i < 32; ++i) {
    int t = tc * 32 + i;
    const unsigned short* ap = f64 + ((size_t)(tile * 512 + t) * 16 + n) * 64 + quad * 8;
    short8 Va0 = *(const short8*)ap;
    short8 Va1 = *(const short8*)(ap + 32);
    unsigned short* pb = pre + (size_t)(tile * 512 + t) * 4096 + n * 64 + quad * 16 + q * 4;
#pragma unroll
    for (int jg = 0; jg < 4; ++jg) {
      float4v acc = {bias[jg], bias[jg], bias[jg], bias[jg]};
      acc = __builtin_amdgcn_mfma_f32_16x16x32_bf16(Va0, Vb[jg][0], acc, 0, 0, 0);
      acc = __builtin_amdgcn_mfma_f32_16x16x32_bf16(Va1, Vb[jg][1], acc, 0, 0, 0);
      unsigned lo = (unsigned)f2bf(acc[0]) | ((unsigned)f2bf(acc[1]) << 16);
      unsigned hi = (unsigned)f2bf(acc[2]) | ((unsigned)f2bf(acc[3]) << 16);
      uint2 v; v.x = lo; v.y = hi;
      *(uint2*)(pb + (size_t)jg * 1024) = v;
    }
  }
}

// ---------------- K2: MFMA LSTM recurrence --------------------------------
// t-loop unrolled by 2 with STATIC even/odd prefetch registers (no rotation
// movs) so vmcnt waits land ~2 steps after issue, hiding HBM/L3 latency.
// combined is written in bf16 (h is bf16 in LDS anyway -> bit-identical).

template <int H, int CH, int STR, int MB, int SCH, int HOFF, bool HOIST>
__device__ __forceinline__ void lstm_core(
    unsigned short* __restrict__ Ab0, unsigned short* __restrict__ Ab1,
    const unsigned short* __restrict__ Bt,
    const float* __restrict__ bi, const float* __restrict__ bh,
    const unsigned short* __restrict__ featp,   // !HOIST only
    const unsigned short* __restrict__ prep_,   // HOIST only (tile base)
    unsigned short* __restrict__ combbase,      // combined (bf16) + coff
    int b0, int mrow0, int j0) {
  constexpr int K = CH * 32;
  constexpr int XSH = MB * SCH * 8;
  constexpr int JQ = H / 4;
  int tid = threadIdx.x;
  int lane = tid & 63, n = lane & 15, quad = lane >> 4;

  // B fragments (+scaled bias if no pre)
  short8 Vb[4][CH];
  float bias[4];
#pragma unroll
  for (int q = 0; q < 4; ++q) {
    int g = q * H + j0 + n;
    if (!HOIST) bias[q] = (bi[g] + bh[g]) * ((q == 2) ? NL2E2 : NL2E);
#pragma unroll
    for (int c = 0; c < CH; ++c)
      Vb[q][c] = *(const short8*)(Bt + (size_t)g * K + c * 32 + quad * 8);
  }

  for (int i = tid; i < MB * STR; i += 256) { Ab0[i] = 0; Ab1[i] = 0; }
  __syncthreads();  // zero-init visible before staging writes (race fix)

  // x staging (fallback/arms): static even/odd regs, load feat[t+3] at step t
  bool st = false;
  unsigned short *xd0 = nullptr, *xd1 = nullptr;
  const unsigned short* fp = nullptr;
  short8 xE, xO;
  if (!HOIST) {
    st = tid < MB * SCH;
    int sm = tid / SCH, sc8 = tid % SCH;
    xd0 = Ab0 + sm * STR + sc8 * 8;
    xd1 = Ab1 + sm * STR + sc8 * 8;
    fp = featp + tid * 8;
    if (st) {
      *(short8*)xd0 = *(const short8*)fp;            // feat[0] -> buf0
      xO = *(const short8*)(fp + XSH);               // feat[1]
      xE = *(const short8*)(fp + 2 * (size_t)XSH);   // feat[2]
    }
    fp += 3 * (size_t)XSH;                            // -> feat[3]
  }

  // pre prefetch (hoist): static even/odd reg pairs
  const unsigned short* ppE = nullptr;
  const unsigned short* ppO = nullptr;
  short8 pE0, pE1, pO0, pO1;
  if (HOIST) {
    const unsigned short* pp0 = prep_ + (size_t)(j0 >> 4) * 1024 + n * 64 + quad * 16;
    pE0 = *(const short8*)pp0;
    pE1 = *(const short8*)(pp0 + 8);
    pO0 = *(const short8*)(pp0 + 4096);
    pO1 = *(const short8*)(pp0 + 4096 + 8);
    ppE = pp0 + 2 * (size_t)4096;   // pre[2]
    ppO = pp0 + 3 * (size_t)4096;   // pre[3]
  }

  float4v cc = {0.f, 0.f, 0.f, 0.f};
  __syncthreads();

  const unsigned short* ard0 = Ab0 + (mrow0 + n) * STR;
  const unsigned short* ard1 = Ab1 + (mrow0 + n) * STR;
  unsigned short* hw0 = Ab0 + (mrow0 + quad * 4) * STR + HOFF + j0 + n;
  unsigned short* hw1 = Ab1 + (mrow0 + quad * 4) * STR + HOFF + j0 + n;

  // comb flush mapping (block-wide, coalesced, bf16)
  int fm = tid / JQ, fjq = tid % JQ;
  const unsigned short* fl0 = Ab0 + fm * STR + HOFF + fjq * 4;
  const unsigned short* fl1 = Ab1 + fm * STR + HOFF + fjq * 4;
  unsigned short* cfp = combbase + ((size_t)(b0 + fm) * TLEN) * HID + fjq * 4;

  for (int tt = 0; tt < TLEN; tt += 2) {
    // ---------------- even step t = tt (reads buf0, writes h to buf1) -----
    {
      const int t = tt;
      if (t > 0) {                       // flush h^{t-1} from buf0
        *(uint2*)cfp = *(const uint2*)fl0;
        cfp += HID;
      }
      short8 Va[CH];
#pragma unroll
      for (int c = 0; c < CH; ++c)
        Va[c] = *(const short8*)(ard0 + c * 32 + quad * 8);

      float4v acc[4];
      if (HOIST) {
#pragma unroll
        for (int r = 0; r < 4; ++r) {
          acc[0][r] = bf2f((unsigned short)pE0[r]);
          acc[1][r] = bf2f((unsigned short)pE0[4 + r]);
          acc[2][r] = bf2f((unsigned short)pE1[r]);
          acc[3][r] = bf2f((unsigned short)pE1[4 + r]);
        }
        if (t + 2 < TLEN) {              // refill even regs (pre[t+2])
          pE0 = *(const short8*)ppE;
          pE1 = *(const short8*)(ppE + 8);
        }
        ppE += 2 * 4096;
      } else {
#pragma unroll
        for (int q = 0; q < 4; ++q)
          acc[q] = (float4v){bias[q], bias[q], bias[q], bias[q]};
      }
#pragma unroll
      for (int q = 0; q < 4; ++q)
#pragma unroll
        for (int c = 0; c < CH; ++c)
          acc[q] = __builtin_amdgcn_mfma_f32_16x16x32_bf16(Va[c], Vb[q][c], acc[q], 0, 0, 0);

      if (!HOIST) {
        if (st) {
          *(short8*)xd1 = xO;                          // feat[t+1] -> buf1
          if (t + 3 < TLEN) xO = *(const short8*)fp;   // feat[t+3]
        }
        fp += XSH;
      }

#pragma unroll
      for (int r = 0; r < 4; ++r) {
        float gi = __builtin_amdgcn_rcpf(1.f + exp2f(acc[0][r]));
        float gf = __builtin_amdgcn_rcpf(1.f + exp2f(acc[1][r]));
        float gg = fmaf(2.f, __builtin_amdgcn_rcpf(1.f + exp2f(acc[2][r])), -1.f);
        float go = __builtin_amdgcn_rcpf(1.f + exp2f(acc[3][r]));
        float cv = fmaf(gf, cc[r], gi * gg);
        cc[r] = cv;
        float th = fmaf(2.f, __builtin_amdgcn_rcpf(1.f + exp2f(cv * NL2E2)), -1.f);
        hw1[r * STR] = f2bf(go * th);
      }
      lds_barrier();
    }
    // ---------------- odd step t = tt+1 (reads buf1, writes h to buf0) ----
    {
      const int t = tt + 1;
      *(uint2*)cfp = *(const uint2*)fl1;   // flush h^{t-1} from buf1
      cfp += HID;
      short8 Va[CH];
#pragma unroll
      for (int c = 0; c < CH; ++c)
        Va[c] = *(const short8*)(ard1 + c * 32 + quad * 8);

      float4v acc[4];
      if (HOIST) {
#pragma unroll
        for (int r = 0; r < 4; ++r) {
          acc[0][r] = bf2f((unsigned short)pO0[r]);
          acc[1][r] = bf2f((unsigned short)pO0[4 + r]);
          acc[2][r] = bf2f((unsigned short)pO1[r]);
          acc[3][r] = bf2f((unsigned short)pO1[4 + r]);
        }
        if (t + 2 < TLEN) {              // refill odd regs (pre[t+2])
          pO0 = *(const short8*)ppO;
          pO1 = *(const short8*)(ppO + 8);
        }
        ppO += 2 * 4096;
      } else {
#pragma unroll
        for (int q = 0; q < 4; ++q)
          acc[q] = (float4v){bias[q], bias[q], bias[q], bias[q]};
      }
#pragma unroll
      for (int q = 0; q < 4; ++q)
#pragma unroll
        for (int c = 0; c < CH; ++c)
          acc[q] = __builtin_amdgcn_mfma_f32_16x16x32_bf16(Va[c], Vb[q][c], acc[q], 0, 0, 0);

      if (!HOIST) {
        if (st) {
          if (t + 1 < TLEN) *(short8*)xd0 = xE;        // feat[t+1] -> buf0
          if (t + 3 < TLEN) xE = *(const short8*)fp;   // feat[t+3]
        }
        fp += XSH;
      }

#pragma unroll
      for (int r = 0; r < 4; ++r) {
        float gi = __builtin_amdgcn_rcpf(1.f + exp2f(acc[0][r]));
        float gf = __builtin_amdgcn_rcpf(1.f + exp2f(acc[1][r]));
        float gg = fmaf(2.f, __builtin_amdgcn_rcpf(1.f + exp2f(acc[2][r])), -1.f);
        float go = __builtin_amdgcn_rcpf(1.f + exp2f(acc[3][r]));
        float cv = fmaf(gf, cc[r], gi * gg);
        cc[r] = cv;
        float th = fmaf(2.f, __builtin_amdgcn_rcpf(1.f + exp2f(cv * NL2E2)), -1.f);
        hw0[r * STR] = f2bf(go * th);
      }
      lds_barrier();
    }
  }

  // final flush: h^{T-1} lives in buf0 (TLEN even)
  *(uint2*)cfp = *(const uint2*)fl0;
}

__global__ __launch_bounds__(256, 1) void lstm_hoist(
    const unsigned short* __restrict__ fAR, const unsigned short* __restrict__ fAL,
    const unsigned short* __restrict__ btH_r, const unsigned short* __restrict__ btH_l,
    const unsigned short* __restrict__ btArm_r, const unsigned short* __restrict__ btArm_l,
    const unsigned short* __restrict__ preR, const unsigned short* __restrict__ preL,
    const float* __restrict__ b1i, const float* __restrict__ b1h,
    const float* __restrict__ b3i, const float* __restrict__ b3h,
    unsigned short* __restrict__ combined) {
  __shared__ __align__(16) unsigned short A0[2304];
  __shared__ __align__(16) unsigned short A1[2304];
  int blk = blockIdx.x;
  int wave = threadIdx.x >> 6;
  if (blk < 16) {           // hands: H=64, MB=16, h-only rows (STR=72)
    int lr = blk >> 3, tl = blk & 7;
    lstm_core<64, 2, 72, 16, 0, 0, true>(
        A0, A1, lr ? btH_l : btH_r, nullptr, nullptr, nullptr,
        (lr ? preL : preR) + (size_t)tl * 512 * 4096,
        combined + (lr ? 96 : 0), tl * 16, 0, wave * 16);
  } else {                  // arms: H=32, MB=32, rows [x8|0|h32] (STR=72)
    int a = blk - 16;
    int la = a >> 2, tl = a & 3;
    lstm_core<32, 2, 72, 32, 1, 32, false>(
        A0, A1, la ? btArm_l : btArm_r, la ? b3i : b1i, la ? b3h : b1h,
        (la ? fAL : fAR) + (size_t)tl * 512 * 256, nullptr,
        combined + (la ? 160 : 64), tl * 32, (wave >> 1) * 16, (wave & 1) * 16);
  }
}

__global__ __launch_bounds__(256, 1) void lstm_fb(
    const unsigned short* __restrict__ fHR, const unsigned short* __restrict__ fHL,
    const unsigned short* __restrict__ fAR, const unsigned short* __restrict__ fAL,
    const unsigned short* __restrict__ btA_r, const unsigned short* __restrict__ btA_l,
    const unsigned short* __restrict__ btArm_r, const unsigned short* __restrict__ btArm_l,
    const float* __restrict__ b0i, const float* __restrict__ b0h,
    const float* __restrict__ b1i, const float* __restrict__ b1h,
    const float* __restrict__ b2i, const float* __restrict__ b2h,
    const float* __restrict__ b3i, const float* __restrict__ b3h,
    unsigned short* __restrict__ combined) {
  __shared__ __align__(16) unsigned short A0[2304];
  __shared__ __align__(16) unsigned short A1[2304];
  int blk = blockIdx.x;
  int wave = threadIdx.x >> 6;
  if (blk < 16) {           // hands: K=128 rows [x48|0|h64] (STR=136)
    int lr = blk >> 3, tl = blk & 7;
    lstm_core<64, 4, 136, 16, 6, 64, false>(
        A0, A1, lr ? btA_l : btA_r, lr ? b2i : b0i, lr ? b2h : b0h,
        (lr ? fHL : fHR) + (size_t)tl * 512 * 768, nullptr,
        combined + (lr ? 96 : 0), tl * 16, 0, wave * 16);
  } else {
    int a = blk - 16;
    int la = a >> 2, tl = a & 3;
    lstm_core<32, 2, 72, 32, 1, 32, false>(
        A0, A1, la ? btArm_l : btArm_r, la ? b3i : b1i, la ? b3h : b1h,
        (la ? fAL : fAR) + (size_t)tl * 512 * 256, nullptr,
        combined + (la ? 160 : 64), tl * 32, (wave >> 1) * 16, (wave & 1) * 16);
  }
}

// ---------------- K3: attention + FC (512 threads, bf16 combined) ---------

__global__ __launch_bounds__(512) void attn_kernel(const unsigned short* __restrict__ combined,
                                                   const float* __restrict__ att_w,
                                                   const float* __restrict__ fc_w,
                                                   const float* __restrict__ fc_b,
                                                   float* __restrict__ dout) {
  __shared__ float sc[TLEN];
  __shared__ float aw[HID];
  __shared__ float pctx[8][HID];
  __shared__ float ctx[HID];
  __shared__ float red[8];
  int b = blockIdx.x, tid = threadIdx.x;
  int lane = tid & 63, wave = tid >> 6;
  const unsigned short* cb = combined + (size_t)b * TLEN * HID;
  if (tid < HID) aw[tid] = att_w[tid];
  __syncthreads();
  float a0 = aw[lane], a1 = aw[lane + 64], a2 = aw[lane + 128];

  int t0 = wave * 64;
  for (int t = t0; t < t0 + 64; t += 2) {
    const unsigned short* r0 = cb + (size_t)t * HID;
    const unsigned short* r1 = r0 + HID;
    float p0 = a0 * bf2f(r0[lane]) + a1 * bf2f(r0[lane + 64]) + a2 * bf2f(r0[lane + 128]);
    float p1 = a0 * bf2f(r1[lane]) + a1 * bf2f(r1[lane + 64]) + a2 * bf2f(r1[lane + 128]);
#pragma unroll
    for (int o = 32; o; o >>= 1) {
      p0 += __shfl_xor(p0, o, 64);
      p1 += __shfl_xor(p1, o, 64);
    }
    if (lane == 0) { sc[t] = p0; sc[t + 1] = p1; }
  }
  __syncthreads();

  float e = sc[tid];
  float lmax = e;
#pragma unroll
  for (int o = 32; o; o >>= 1) lmax = fmaxf(lmax, __shfl_xor(lmax, o, 64));
  if (lane == 0) red[wave] = lmax;
  __syncthreads();
  float m = red[0];
#pragma unroll
  for (int w = 1; w < 8; ++w) m = fmaxf(m, red[w]);
  __syncthreads();
  float ex = __expf(e - m);
  float ls = ex;
#pragma unroll
  for (int o = 32; o; o >>= 1) ls += __shfl_xor(ls, o, 64);
  if (lane == 0) red[wave] = ls;
  __syncthreads();
  float S = red[0];
#pragma unroll
  for (int w = 1; w < 8; ++w) S += red[w];
  float wgt = ex / S;
  sc[tid] = wgt;
  dout[BATCH * NC + b * TLEN + tid] = wgt;  // weights (B,T,1)
  __syncthreads();

#pragma unroll
  for (int p = 0; p < 3; ++p) {
    int h = p * 64 + lane;
    float c0 = 0.f, c1 = 0.f, c2 = 0.f, c3 = 0.f;
    for (int t = t0; t < t0 + 64; t += 4) {
      c0 += sc[t] * bf2f(cb[(size_t)t * HID + h]);
      c1 += sc[t + 1] * bf2f(cb[(size_t)(t + 1) * HID + h]);
      c2 += sc[t + 2] * bf2f(cb[(size_t)(t + 2) * HID + h]);
      c3 += sc[t + 3] * bf2f(cb[(size_t)(t + 3) * HID + h]);
    }
    pctx[wave][h] = (c0 + c1) + (c2 + c3);
  }
  __syncthreads();
  if (tid < HID) {
    float s = pctx[0][tid];
#pragma unroll
    for (int w = 1; w < 8; ++w) s += pctx[w][tid];
    ctx[tid] = s;
  }
  __syncthreads();

  if (tid < NC) {
    const float* wr = fc_w + (size_t)tid * HID;
    float s0 = fc_b[tid], s1 = 0.f, s2 = 0.f, s3 = 0.f;
#pragma unroll
    for (int h = 0; h < HID; h += 4) {
      s0 += ctx[h] * wr[h];
      s1 += ctx[h + 1] * wr[h + 1];
      s2 += ctx[h + 2] * wr[h + 2];
      s3 += ctx[h + 3] * wr[h + 3];
    }
    dout[b * NC + tid] = (s0 + s1) + (s2 + s3);  // logits (B,250)
  }
}

// ---------------- launcher ----------------

extern "C" void kernel_launch(void* const* d_in, const int* in_sizes, int n_in,
                              void* d_out, int out_size, void* d_ws, size_t ws_size,
                              hipStream_t stream) {
  const float* x = (const float*)d_in[0];
  const float* wih_rh = (const float*)d_in[1];
  const float* whh_rh = (const float*)d_in[2];
  const float* bih_rh = (const float*)d_in[3];
  const float* bhh_rh = (const float*)d_in[4];
  const float* wih_ra = (const float*)d_in[5];
  const float* whh_ra = (const float*)d_in[6];
  const float* bih_ra = (const float*)d_in[7];
  const float* bhh_ra = (const float*)d_in[8];
  const float* wih_lh = (const float*)d_in[9];
  const float* whh_lh = (const float*)d_in[10];
  const float* bih_lh = (const float*)d_in[11];
  const float* bhh_lh = (const float*)d_in[12];
  const float* wih_la = (const float*)d_in[13];
  const float* whh_la = (const float*)d_in[14];
  const float* bih_la = (const float*)d_in[15];
  const float* bhh_la = (const float*)d_in[16];
  const float* att_w = (const float*)d_in[17];
  const float* fc_w = (const float*)d_in[18];
  const float* fc_b = (const float*)d_in[19];

  const size_t SZ_COMB = (size_t)BATCH * TLEN * HID * 2;     // 25,165,824 (bf16)
  const size_t SZ_FARM = (size_t)4 * TLEN * 32 * 8 * 2;      // 2,097,152
  const size_t SZ_F64  = (size_t)8 * TLEN * 16 * 64 * 2;     // 8,388,608
  const size_t SZ_F48  = (size_t)8 * TLEN * 16 * 48 * 2;     // 6,291,456
  const size_t SZ_PRE  = (size_t)8 * TLEN * 4096 * 2;        // 33,554,432
  const size_t NEED_FULL = SZ_COMB + 2 * SZ_FARM + 2 * SZ_F64 + 2 * SZ_PRE +
                           2 * 32768 + 2 * 32768 + 2 * 16384; // ~113.5 MB
  bool hoist = ws_size >= NEED_FULL;

  char* p = (char*)d_ws;
  unsigned short* combined = (unsigned short*)p; p += SZ_COMB;
  unsigned short* fAR = (unsigned short*)p; p += SZ_FARM;
  unsigned short* fAL = (unsigned short*)p; p += SZ_FARM;
  unsigned short *fHR, *fHL, *preR = nullptr, *preL = nullptr;
  unsigned short *btA_r, *btA_l, *btH_r = nullptr, *btH_l = nullptr, *btArm_r, *btArm_l;
  if (hoist) {
    fHR = (unsigned short*)p; p += SZ_F64;
    fHL = (unsigned short*)p; p += SZ_F64;
    preR = (unsigned short*)p; p += SZ_PRE;
    preL = (unsigned short*)p; p += SZ_PRE;
    btA_r = (unsigned short*)p; p += 32768;
    btA_l = (unsigned short*)p; p += 32768;
    btH_r = (unsigned short*)p; p += 32768;
    btH_l = (unsigned short*)p; p += 32768;
  } else {
    fHR = (unsigned short*)p; p += SZ_F48;
    fHL = (unsigned short*)p; p += SZ_F48;
    btA_r = (unsigned short*)p; p += 65536;
    btA_l = (unsigned short*)p; p += 65536;
    btH_r = btA_r; btH_l = btA_l;  // unused in fb
  }
  btArm_r = (unsigned short*)p; p += 16384;
  btArm_l = (unsigned short*)p;

  prep_kernel<<<dim3((BATCH * TLEN + 255) / 256), 256, 0, stream>>>(
      x, fHR, fHL, fAR, fAL, hoist ? 64 : 48);
  pack_kernel<<<dim3(6), 256, 0, stream>>>(
      hoist ? 1 : 0,
      wih_rh, whh_rh, wih_ra, whh_ra, wih_lh, whh_lh, wih_la, whh_la,
      btA_r, btA_l, btH_r, btH_l, btArm_r, btArm_l);
  if (hoist) {
    pregemm_kernel<<<dim3(256), 256, 0, stream>>>(
        fHR, fHL, btA_r, btA_l, bih_rh, bhh_rh, bih_lh, bhh_lh, preR, preL);
    lstm_hoist<<<dim3(24), 256, 0, stream>>>(
        fAR, fAL, btH_r, btH_l, btArm_r, btArm_l, preR, preL,
        bih_ra, bhh_ra, bih_la, bhh_la, combined);
  } else {
    lstm_fb<<<dim3(24), 256, 0, stream>>>(
        fHR, fHL, fAR, fAL, btA_r, btA_l, btArm_r, btArm_l,
        bih_rh, bhh_rh, bih_ra, bhh_ra, bih_lh, bhh_lh, bih_la, bhh_la, combined);
  }
  attn_kernel<<<dim3(BATCH), 512, 0, stream>>>(combined, att_w, fc_w, fc_b, (float*)d_out);
}

// Round 2
// 438.782 us; speedup vs baseline: 1.2586x; 1.2586x over previous
//
#include <hip/hip_runtime.h>
#include <math.h>

#define BATCH 128
#define TLEN 512
#define XF 266
#define HID 192
#define NC 250

typedef __attribute__((ext_vector_type(8))) short short8;
typedef __attribute__((ext_vector_type(4))) float float4v;

#define NL2E  -1.4426950408889634f
#define NL2E2 -2.8853900817779268f

// fp32 -> bf16 (RNE)
__device__ __forceinline__ unsigned short f2bf(float f) {
  unsigned u = __float_as_uint(f);
  u += 0x7FFF + ((u >> 16) & 1);
  return (unsigned short)(u >> 16);
}
__device__ __forceinline__ float bf2f(unsigned short s) {
  return __uint_as_float(((unsigned)s) << 16);
}

// single-instruction exp2 (v_exp_f32)
__device__ __forceinline__ float exp2i(float x) {
#if __has_builtin(__builtin_amdgcn_exp2f)
  return __builtin_amdgcn_exp2f(x);
#else
  float r;
  asm("v_exp_f32 %0, %1" : "=v"(r) : "v"(x));
  return r;
#endif
}

// LDS-only barrier: does NOT drain vmcnt.
__device__ __forceinline__ void lds_barrier() {
  asm volatile("s_waitcnt lgkmcnt(0)\n\ts_barrier" ::: "memory");
}

// ---------------- K1: feature prep --------------------------------------
// hoist mode: hands [tile16][t][m16][64] with batch b -> tile b>>3,
//   row (v>>1)*4+(v&1) (v=b&7)  (half-row scatter: rows {4q+r, r<2})
//   arms [tile8][t][m32][8], b -> tile b>>4, row (v>>3)*16+((v&7)>>1)*4+(v&1)
// fb mode: old full-row layouts (hands [tile8][t][m16][48], arms [tile4][t][m32][8])

__device__ __forceinline__ void norm_hand(const float* __restrict__ xp,
                                          unsigned short* __restrict__ fp,
                                          int p0, int refp, int hs) {
  float rx = xp[2 * refp], ry = xp[2 * refp + 1];
  float px[21], py[21];
  float minx = 1e30f, maxx = -1e30f, miny = 1e30f, maxy = -1e30f;
#pragma unroll
  for (int i = 0; i < 21; ++i) {
    float ax = xp[2 * (p0 + i)] - rx;
    float ay = xp[2 * (p0 + i) + 1] - ry;
    px[i] = ax; py[i] = ay;
    minx = fminf(minx, ax); maxx = fmaxf(maxx, ax);
    miny = fminf(miny, ay); maxy = fmaxf(maxy, ay);
  }
  float s = fmaxf(maxx - minx, maxy - miny);
  if (s == 0.f) s = 1.f;
  float inv = 1.f / s;
#pragma unroll
  for (int i = 0; i < 21; ++i) {
    fp[2 * i] = f2bf(px[i] * inv);
    fp[2 * i + 1] = f2bf(py[i] * inv);
  }
  for (int i = 42; i < hs; ++i) fp[i] = 0;
}

__device__ __forceinline__ void norm_arm(const float* __restrict__ xp,
                                         unsigned short* __restrict__ fp,
                                         int a, int b, int c) {
  float rx = xp[0], ry = xp[1];
  float x0 = xp[2 * a] - rx, y0 = xp[2 * a + 1] - ry;
  float x1 = xp[2 * b] - rx, y1 = xp[2 * b + 1] - ry;
  float x2 = xp[2 * c] - rx, y2 = xp[2 * c + 1] - ry;
  float w = fmaxf(fmaxf(x0, x1), x2) - fminf(fminf(x0, x1), x2);
  float h = fmaxf(fmaxf(y0, y1), y2) - fminf(fminf(y0, y1), y2);
  float s = fmaxf(w, h);
  if (s == 0.f) s = 1.f;
  float inv = 1.f / s;
  fp[0] = f2bf(x0 * inv); fp[1] = f2bf(y0 * inv);
  fp[2] = f2bf(x1 * inv); fp[3] = f2bf(y1 * inv);
  fp[4] = f2bf(x2 * inv); fp[5] = f2bf(y2 * inv);
  fp[6] = 0; fp[7] = 0;
}

__global__ __launch_bounds__(256) void prep_kernel(
    const float* __restrict__ x,
    unsigned short* __restrict__ fHR, unsigned short* __restrict__ fHL,
    unsigned short* __restrict__ fAR, unsigned short* __restrict__ fAL,
    int mode) {
  int idx = blockIdx.x * 256 + threadIdx.x;
  if (idx >= BATCH * TLEN) return;
  int b = idx >> 9, t = idx & 511;
  const float* xp = x + (size_t)idx * XF;
  size_t hoff, aoff;
  int hs;
  if (mode) {
    hs = 64;
    int vh = b & 7;
    int rowh = (vh >> 1) * 4 + (vh & 1);
    hoff = (((size_t)(b >> 3) * TLEN + t) * 16 + rowh) * 64;
    int va = b & 15;
    int rowa = (va >> 3) * 16 + ((va & 7) >> 1) * 4 + (va & 1);
    aoff = (((size_t)(b >> 4) * TLEN + t) * 32 + rowa) * 8;
  } else {
    hs = 48;
    hoff = (((size_t)(b >> 4) * TLEN + t) * 16 + (b & 15)) * 48;
    aoff = (((size_t)(b >> 5) * TLEN + t) * 32 + (b & 31)) * 8;
  }
  norm_hand(xp, fHR + hoff, 112, 10, hs);  // right hand, ref pt 10
  norm_hand(xp, fHL + hoff, 91, 9, hs);    // left hand, ref pt 9
  norm_arm (xp, fAR + aoff, 6, 8, 10);     // right arm
  norm_arm (xp, fAL + aoff, 5, 7, 9);      // left arm
}

// ---------------- K1b: weight packing -----------------------------------
// Gate weights pre-scaled by -log2(e) (i,f,o) / -2log2(e) (g) so the
// recurrence uses bare v_exp_f32.

__global__ __launch_bounds__(256) void pack_kernel(
    int mode,
    const float* __restrict__ wi_rh, const float* __restrict__ wh_rh,
    const float* __restrict__ wi_ra, const float* __restrict__ wh_ra,
    const float* __restrict__ wi_lh, const float* __restrict__ wh_lh,
    const float* __restrict__ wi_la, const float* __restrict__ wh_la,
    unsigned short* __restrict__ btA_r, unsigned short* __restrict__ btA_l,
    unsigned short* __restrict__ btH_r, unsigned short* __restrict__ btH_l,
    unsigned short* __restrict__ btArm_r, unsigned short* __restrict__ btArm_l) {
  int blk = blockIdx.x, tid = threadIdx.x;
  if (blk < 2) {
    const float* wi = blk ? wi_lh : wi_rh;
    const float* wh = blk ? wh_lh : wh_rh;
    unsigned short* dst = blk ? btA_l : btA_r;
    if (mode) {
      for (int i = tid; i < 256 * 64; i += 256) {
        int g = i >> 6, k = i & 63;
        float s = ((g >> 6) == 2) ? NL2E2 : NL2E;
        dst[i] = f2bf(k < 42 ? wi[g * 42 + k] * s : 0.f);
      }
    } else {
      for (int i = tid; i < 256 * 128; i += 256) {
        int g = i >> 7, k = i & 127;
        float s = ((g >> 6) == 2) ? NL2E2 : NL2E;
        float v = (k < 42) ? wi[g * 42 + k] : (k < 64 ? 0.f : wh[g * 64 + (k - 64)]);
        dst[i] = f2bf(v * s);
      }
    }
  } else if (blk < 4) {
    if (mode) {
      const float* wh = (blk == 3) ? wh_lh : wh_rh;
      unsigned short* dst = (blk == 3) ? btH_l : btH_r;
      for (int i = tid; i < 256 * 64; i += 256) {
        int g = i >> 6;
        float s = ((g >> 6) == 2) ? NL2E2 : NL2E;
        dst[i] = f2bf(wh[i] * s);
      }
    }
  } else {
    const float* wi = (blk == 5) ? wi_la : wi_ra;
    const float* wh = (blk == 5) ? wh_la : wh_ra;
    unsigned short* dst = (blk == 5) ? btArm_l : btArm_r;
    for (int i = tid; i < 128 * 64; i += 256) {
      int g = i >> 6, k = i & 63;
      float s = ((g >> 5) == 2) ? NL2E2 : NL2E;
      float v = (k < 6) ? wi[g * 6 + k] : (k < 32 ? 0.f : wh[g * 32 + (k - 32)]);
      dst[i] = f2bf(v * s);
    }
  }
}

// ---------------- K1c: input-projection pre-GEMM (hoist mode) ------------
// Packed pre (valid rows r<2 only): per (tile,t) 2048 shorts:
//   offset = jt*512 + n*32 + quad*8 + q*2 + r
// Consumer lane (n,quad) of wave jt reads one short8 = {q0r0,q0r1,...,q3r1}.
// 512 blocks = (lr, tile16, tc16); wave = gate-quad q; 32 t per block.

__global__ __launch_bounds__(256, 1) void pregemm_kernel(
    const unsigned short* __restrict__ f64R, const unsigned short* __restrict__ f64L,
    const unsigned short* __restrict__ btiR, const unsigned short* __restrict__ btiL,
    const float* __restrict__ biR, const float* __restrict__ bhR,
    const float* __restrict__ biL, const float* __restrict__ bhL,
    unsigned short* __restrict__ preR, unsigned short* __restrict__ preL) {
  int bx = blockIdx.x;
  int lr = bx >> 8, tile = (bx >> 4) & 15, tc = bx & 15;
  const unsigned short* f64 = lr ? f64L : f64R;
  const unsigned short* bti = lr ? btiL : btiR;
  const float* bi = lr ? biL : biR;
  const float* bh = lr ? bhL : bhR;
  unsigned short* pre = lr ? preL : preR;
  int tid = threadIdx.x, lane = tid & 63;
  int q = tid >> 6, n = lane & 15, quad = lane >> 4;
  float sq = (q == 2) ? NL2E2 : NL2E;

  short8 Vb[4][2];
  float bias[4];
#pragma unroll
  for (int jg = 0; jg < 4; ++jg) {
    int g = q * 64 + jg * 16 + n;
    bias[jg] = (bi[g] + bh[g]) * sq;
#pragma unroll
    for (int c = 0; c < 2; ++c)
      Vb[jg][c] = *(const short8*)(bti + (size_t)g * 64 + c * 32 + quad * 8);
  }

  for (int i = 0; i < 32; ++i) {
    int t = tc * 32 + i;
    const unsigned short* ap = f64 + ((size_t)(tile * 512 + t) * 16 + n) * 64 + quad * 8;
    short8 Va0 = *(const short8*)ap;
    short8 Va1 = *(const short8*)(ap + 32);
    unsigned short* pb = pre + (size_t)(tile * 512 + t) * 2048 + n * 32 + quad * 8 + q * 2;
#pragma unroll
    for (int jg = 0; jg < 4; ++jg) {
      float4v acc = {bias[jg], bias[jg], bias[jg], bias[jg]};
      acc = __builtin_amdgcn_mfma_f32_16x16x32_bf16(Va0, Vb[jg][0], acc, 0, 0, 0);
      acc = __builtin_amdgcn_mfma_f32_16x16x32_bf16(Va1, Vb[jg][1], acc, 0, 0, 0);
      unsigned w = (unsigned)f2bf(acc[0]) | ((unsigned)f2bf(acc[1]) << 16);
      *(unsigned*)(pb + (size_t)jg * 512) = w;   // rows r=0,1 only
    }
  }
}

// ---------------- K2: MFMA LSTM recurrence --------------------------------
// RV = valid accumulator rows per lane (2 in half-row hoist tiling, 4 in fb).
// Garbage MFMA rows stay zero (hands) or hold discarded junk (arms) and are
// never activated/flushed. t-loop unrolled x2 with static even/odd prefetch.

template <int H, int CH, int STR, int MB, int SCH, int HOFF, bool HOIST, int RV>
__device__ __forceinline__ void lstm_core(
    unsigned short* __restrict__ Ab0, unsigned short* __restrict__ Ab1,
    const unsigned short* __restrict__ Bt,
    const float* __restrict__ bi, const float* __restrict__ bh,
    const unsigned short* __restrict__ featp,   // !HOIST only
    const unsigned short* __restrict__ prep_,   // HOIST only (tile base)
    unsigned short* __restrict__ combbase,      // combined (bf16) + coff
    int b0, int mrow0, int j0) {
  constexpr int K = CH * 32;
  constexpr int XSH = MB * SCH * 8;
  constexpr int JQ = H / 4;
  constexpr int VR = (RV == 4) ? MB : MB / 2;   // valid rows per instance
  int tid = threadIdx.x;
  int lane = tid & 63, n = lane & 15, quad = lane >> 4;

  // B fragments (+scaled bias if no pre)
  short8 Vb[4][CH];
  float bias[4];
#pragma unroll
  for (int q = 0; q < 4; ++q) {
    int g = q * H + j0 + n;
    if (!HOIST) bias[q] = (bi[g] + bh[g]) * ((q == 2) ? NL2E2 : NL2E);
#pragma unroll
    for (int c = 0; c < CH; ++c)
      Vb[q][c] = *(const short8*)(Bt + (size_t)g * K + c * 32 + quad * 8);
  }

  for (int i = tid; i < MB * STR; i += 256) { Ab0[i] = 0; Ab1[i] = 0; }
  __syncthreads();  // zero-init visible before staging writes

  // x staging (fallback/arms): static even/odd regs
  bool st = false;
  unsigned short *xd0 = nullptr, *xd1 = nullptr;
  const unsigned short* fp = nullptr;
  short8 xE, xO;
  if (!HOIST) {
    st = tid < MB * SCH;
    int sm = tid / SCH, sc8 = tid % SCH;
    xd0 = Ab0 + sm * STR + sc8 * 8;
    xd1 = Ab1 + sm * STR + sc8 * 8;
    fp = featp + tid * 8;
    if (st) {
      *(short8*)xd0 = *(const short8*)fp;            // feat[0] -> buf0
      xO = *(const short8*)(fp + XSH);               // feat[1]
      xE = *(const short8*)(fp + 2 * (size_t)XSH);   // feat[2]
    }
    fp += 3 * (size_t)XSH;                            // -> feat[3]
  }

  // packed-pre prefetch (hoist): one short8 per step, static even/odd regs
  const unsigned short* ppE = nullptr;
  const unsigned short* ppO = nullptr;
  short8 pE, pO;
  if (HOIST) {
    const unsigned short* pp0 = prep_ + (size_t)j0 * 32 + n * 32 + quad * 8;
    pE = *(const short8*)pp0;             // pre[0]
    pO = *(const short8*)(pp0 + 2048);    // pre[1]
    ppE = pp0 + 2 * (size_t)2048;         // pre[2]
    ppO = pp0 + 3 * (size_t)2048;         // pre[3]
  }

  float4v cc = {0.f, 0.f, 0.f, 0.f};
  __syncthreads();

  const unsigned short* ard0 = Ab0 + (mrow0 + n) * STR;
  const unsigned short* ard1 = Ab1 + (mrow0 + n) * STR;
  unsigned short* hw0 = Ab0 + (mrow0 + quad * 4) * STR + HOFF + j0 + n;
  unsigned short* hw1 = Ab1 + (mrow0 + quad * 4) * STR + HOFF + j0 + n;

  // comb flush mapping (VR*JQ threads, coalesced, bf16)
  int vi = tid / JQ, fjq = tid % JQ;
  bool fon = tid < VR * JQ;
  int fm = (RV == 4) ? vi
                     : ((vi >> 3) * 16 + ((vi & 7) >> 1) * 4 + (vi & 1));
  const unsigned short* fl0 = Ab0 + fm * STR + HOFF + fjq * 4;
  const unsigned short* fl1 = Ab1 + fm * STR + HOFF + fjq * 4;
  unsigned short* cfp = combbase + ((size_t)(b0 + vi) * TLEN) * HID + fjq * 4;

#define ACT_AND_WRITE(hw)                                                     \
  _Pragma("unroll")                                                           \
  for (int r = 0; r < RV; ++r) {                                              \
    float Ei = exp2i(acc[0][r]);                                              \
    float Ef = exp2i(acc[1][r]);                                              \
    float Eg = exp2i(acc[2][r]);                                              \
    float Eo = exp2i(acc[3][r]);                                              \
    float gf = __builtin_amdgcn_rcpf(1.f + Ef);                               \
    float ig = (1.f - Eg) * __builtin_amdgcn_rcpf((1.f + Ei) * (1.f + Eg));   \
    float cv = fmaf(gf, cc[r], ig);                                           \
    cc[r] = cv;                                                               \
    float Ec = exp2i(cv * NL2E2);                                             \
    float hv = (1.f - Ec) * __builtin_amdgcn_rcpf((1.f + Eo) * (1.f + Ec));   \
    (hw)[r * STR] = f2bf(hv);                                                 \
  }

  for (int tt = 0; tt < TLEN; tt += 2) {
    // ---------------- even step t = tt (reads buf0, writes h to buf1) -----
    {
      const int t = tt;
      if (fon && t > 0) {                 // flush h^{t-1} from buf0
        *(uint2*)cfp = *(const uint2*)fl0;
        cfp += HID;
      }
      short8 Va[CH];
#pragma unroll
      for (int c = 0; c < CH; ++c)
        Va[c] = *(const short8*)(ard0 + c * 32 + quad * 8);

      float4v acc[4];
      if (HOIST) {
#pragma unroll
        for (int q = 0; q < 4; ++q) {
          acc[q][0] = bf2f((unsigned short)pE[q * 2]);
          acc[q][1] = bf2f((unsigned short)pE[q * 2 + 1]);
          acc[q][2] = 0.f; acc[q][3] = 0.f;
        }
        if (t + 2 < TLEN) pE = *(const short8*)ppE;   // refill (pre[t+2])
        ppE += 2 * (size_t)2048;
      } else {
#pragma unroll
        for (int q = 0; q < 4; ++q)
          acc[q] = (float4v){bias[q], bias[q], bias[q], bias[q]};
      }
#pragma unroll
      for (int q = 0; q < 4; ++q)
#pragma unroll
        for (int c = 0; c < CH; ++c)
          acc[q] = __builtin_amdgcn_mfma_f32_16x16x32_bf16(Va[c], Vb[q][c], acc[q], 0, 0, 0);

      if (!HOIST) {
        if (st) {
          *(short8*)xd1 = xO;                          // feat[t+1] -> buf1
          if (t + 3 < TLEN) xO = *(const short8*)fp;   // feat[t+3]
        }
        fp += XSH;
      }

      ACT_AND_WRITE(hw1)
      lds_barrier();
    }
    // ---------------- odd step t = tt+1 (reads buf1, writes h to buf0) ----
    {
      const int t = tt + 1;
      if (fon) {                           // flush h^{t-1} from buf1
        *(uint2*)cfp = *(const uint2*)fl1;
        cfp += HID;
      }
      short8 Va[CH];
#pragma unroll
      for (int c = 0; c < CH; ++c)
        Va[c] = *(const short8*)(ard1 + c * 32 + quad * 8);

      float4v acc[4];
      if (HOIST) {
#pragma unroll
        for (int q = 0; q < 4; ++q) {
          acc[q][0] = bf2f((unsigned short)pO[q * 2]);
          acc[q][1] = bf2f((unsigned short)pO[q * 2 + 1]);
          acc[q][2] = 0.f; acc[q][3] = 0.f;
        }
        if (t + 2 < TLEN) pO = *(const short8*)ppO;   // refill (pre[t+2])
        ppO += 2 * (size_t)2048;
      } else {
#pragma unroll
        for (int q = 0; q < 4; ++q)
          acc[q] = (float4v){bias[q], bias[q], bias[q], bias[q]};
      }
#pragma unroll
      for (int q = 0; q < 4; ++q)
#pragma unroll
        for (int c = 0; c < CH; ++c)
          acc[q] = __builtin_amdgcn_mfma_f32_16x16x32_bf16(Va[c], Vb[q][c], acc[q], 0, 0, 0);

      if (!HOIST) {
        if (st) {
          if (t + 1 < TLEN) *(short8*)xd0 = xE;        // feat[t+1] -> buf0
          if (t + 3 < TLEN) xE = *(const short8*)fp;   // feat[t+3]
        }
        fp += XSH;
      }

      ACT_AND_WRITE(hw0)
      lds_barrier();
    }
  }

  // final flush: h^{T-1} lives in buf0 (TLEN even)
  if (fon) *(uint2*)cfp = *(const uint2*)fl0;
#undef ACT_AND_WRITE
}

__global__ __launch_bounds__(256, 1) void lstm_hoist(
    const unsigned short* __restrict__ fAR, const unsigned short* __restrict__ fAL,
    const unsigned short* __restrict__ btH_r, const unsigned short* __restrict__ btH_l,
    const unsigned short* __restrict__ btArm_r, const unsigned short* __restrict__ btArm_l,
    const unsigned short* __restrict__ preR, const unsigned short* __restrict__ preL,
    const float* __restrict__ b1i, const float* __restrict__ b1h,
    const float* __restrict__ b3i, const float* __restrict__ b3h,
    unsigned short* __restrict__ combined) {
  __shared__ __align__(16) unsigned short A0[2304];
  __shared__ __align__(16) unsigned short A1[2304];
  int blk = blockIdx.x;
  int wave = threadIdx.x >> 6;
  if (blk < 32) {           // hands: H=64, 16 tiles x 8 batch (half-row)
    int lr = blk >> 4, tl = blk & 15;
    lstm_core<64, 2, 72, 16, 0, 0, true, 2>(
        A0, A1, lr ? btH_l : btH_r, nullptr, nullptr, nullptr,
        (lr ? preL : preR) + (size_t)tl * 512 * 2048,
        combined + (lr ? 96 : 0), tl * 8, 0, wave * 16);
  } else {                  // arms: H=32, 8 tiles x 16 batch (half-row)
    int a = blk - 32;
    int la = a >> 3, tl = a & 7;
    lstm_core<32, 2, 72, 32, 1, 32, false, 2>(
        A0, A1, la ? btArm_l : btArm_r, la ? b3i : b1i, la ? b3h : b1h,
        (la ? fAL : fAR) + (size_t)tl * 512 * 256, nullptr,
        combined + (la ? 160 : 64), tl * 16, (wave >> 1) * 16, (wave & 1) * 16);
  }
}

__global__ __launch_bounds__(256, 1) void lstm_fb(
    const unsigned short* __restrict__ fHR, const unsigned short* __restrict__ fHL,
    const unsigned short* __restrict__ fAR, const unsigned short* __restrict__ fAL,
    const unsigned short* __restrict__ btA_r, const unsigned short* __restrict__ btA_l,
    const unsigned short* __restrict__ btArm_r, const unsigned short* __restrict__ btArm_l,
    const float* __restrict__ b0i, const float* __restrict__ b0h,
    const float* __restrict__ b1i, const float* __restrict__ b1h,
    const float* __restrict__ b2i, const float* __restrict__ b2h,
    const float* __restrict__ b3i, const float* __restrict__ b3h,
    unsigned short* __restrict__ combined) {
  __shared__ __align__(16) unsigned short A0[2304];
  __shared__ __align__(16) unsigned short A1[2304];
  int blk = blockIdx.x;
  int wave = threadIdx.x >> 6;
  if (blk < 16) {           // hands: K=128 rows [x48|0|h64] (STR=136)
    int lr = blk >> 3, tl = blk & 7;
    lstm_core<64, 4, 136, 16, 6, 64, false, 4>(
        A0, A1, lr ? btA_l : btA_r, lr ? b2i : b0i, lr ? b2h : b0h,
        (lr ? fHL : fHR) + (size_t)tl * 512 * 768, nullptr,
        combined + (lr ? 96 : 0), tl * 16, 0, wave * 16);
  } else {
    int a = blk - 16;
    int la = a >> 2, tl = a & 3;
    lstm_core<32, 2, 72, 32, 1, 32, false, 4>(
        A0, A1, la ? btArm_l : btArm_r, la ? b3i : b1i, la ? b3h : b1h,
        (la ? fAL : fAR) + (size_t)tl * 512 * 256, nullptr,
        combined + (la ? 160 : 64), tl * 32, (wave >> 1) * 16, (wave & 1) * 16);
  }
}

// ---------------- K3: attention + FC (512 threads, bf16 combined) ---------

__global__ __launch_bounds__(512) void attn_kernel(const unsigned short* __restrict__ combined,
                                                   const float* __restrict__ att_w,
                                                   const float* __restrict__ fc_w,
                                                   const float* __restrict__ fc_b,
                                                   float* __restrict__ dout) {
  __shared__ float sc[TLEN];
  __shared__ float aw[HID];
  __shared__ float pctx[8][HID];
  __shared__ float ctx[HID];
  __shared__ float red[8];
  int b = blockIdx.x, tid = threadIdx.x;
  int lane = tid & 63, wave = tid >> 6;
  const unsigned short* cb = combined + (size_t)b * TLEN * HID;
  if (tid < HID) aw[tid] = att_w[tid];
  __syncthreads();
  float a0 = aw[lane], a1 = aw[lane + 64], a2 = aw[lane + 128];

  int t0 = wave * 64;
  for (int t = t0; t < t0 + 64; t += 2) {
    const unsigned short* r0 = cb + (size_t)t * HID;
    const unsigned short* r1 = r0 + HID;
    float p0 = a0 * bf2f(r0[lane]) + a1 * bf2f(r0[lane + 64]) + a2 * bf2f(r0[lane + 128]);
    float p1 = a0 * bf2f(r1[lane]) + a1 * bf2f(r1[lane + 64]) + a2 * bf2f(r1[lane + 128]);
#pragma unroll
    for (int o = 32; o; o >>= 1) {
      p0 += __shfl_xor(p0, o, 64);
      p1 += __shfl_xor(p1, o, 64);
    }
    if (lane == 0) { sc[t] = p0; sc[t + 1] = p1; }
  }
  __syncthreads();

  float e = sc[tid];
  float lmax = e;
#pragma unroll
  for (int o = 32; o; o >>= 1) lmax = fmaxf(lmax, __shfl_xor(lmax, o, 64));
  if (lane == 0) red[wave] = lmax;
  __syncthreads();
  float m = red[0];
#pragma unroll
  for (int w = 1; w < 8; ++w) m = fmaxf(m, red[w]);
  __syncthreads();
  float ex = __expf(e - m);
  float ls = ex;
#pragma unroll
  for (int o = 32; o; o >>= 1) ls += __shfl_xor(ls, o, 64);
  if (lane == 0) red[wave] = ls;
  __syncthreads();
  float S = red[0];
#pragma unroll
  for (int w = 1; w < 8; ++w) S += red[w];
  float wgt = ex / S;
  sc[tid] = wgt;
  dout[BATCH * NC + b * TLEN + tid] = wgt;  // weights (B,T,1)
  __syncthreads();

#pragma unroll
  for (int p = 0; p < 3; ++p) {
    int h = p * 64 + lane;
    float c0 = 0.f, c1 = 0.f, c2 = 0.f, c3 = 0.f;
    for (int t = t0; t < t0 + 64; t += 4) {
      c0 += sc[t] * bf2f(cb[(size_t)t * HID + h]);
      c1 += sc[t + 1] * bf2f(cb[(size_t)(t + 1) * HID + h]);
      c2 += sc[t + 2] * bf2f(cb[(size_t)(t + 2) * HID + h]);
      c3 += sc[t + 3] * bf2f(cb[(size_t)(t + 3) * HID + h]);
    }
    pctx[wave][h] = (c0 + c1) + (c2 + c3);
  }
  __syncthreads();
  if (tid < HID) {
    float s = pctx[0][tid];
#pragma unroll
    for (int w = 1; w < 8; ++w) s += pctx[w][tid];
    ctx[tid] = s;
  }
  __syncthreads();

  if (tid < NC) {
    const float* wr = fc_w + (size_t)tid * HID;
    float s0 = fc_b[tid], s1 = 0.f, s2 = 0.f, s3 = 0.f;
#pragma unroll
    for (int h = 0; h < HID; h += 4) {
      s0 += ctx[h] * wr[h];
      s1 += ctx[h + 1] * wr[h + 1];
      s2 += ctx[h + 2] * wr[h + 2];
      s3 += ctx[h + 3] * wr[h + 3];
    }
    dout[b * NC + tid] = (s0 + s1) + (s2 + s3);  // logits (B,250)
  }
}

// ---------------- launcher ----------------

extern "C" void kernel_launch(void* const* d_in, const int* in_sizes, int n_in,
                              void* d_out, int out_size, void* d_ws, size_t ws_size,
                              hipStream_t stream) {
  const float* x = (const float*)d_in[0];
  const float* wih_rh = (const float*)d_in[1];
  const float* whh_rh = (const float*)d_in[2];
  const float* bih_rh = (const float*)d_in[3];
  const float* bhh_rh = (const float*)d_in[4];
  const float* wih_ra = (const float*)d_in[5];
  const float* whh_ra = (const float*)d_in[6];
  const float* bih_ra = (const float*)d_in[7];
  const float* bhh_ra = (const float*)d_in[8];
  const float* wih_lh = (const float*)d_in[9];
  const float* whh_lh = (const float*)d_in[10];
  const float* bih_lh = (const float*)d_in[11];
  const float* bhh_lh = (const float*)d_in[12];
  const float* wih_la = (const float*)d_in[13];
  const float* whh_la = (const float*)d_in[14];
  const float* bih_la = (const float*)d_in[15];
  const float* bhh_la = (const float*)d_in[16];
  const float* att_w = (const float*)d_in[17];
  const float* fc_w = (const float*)d_in[18];
  const float* fc_b = (const float*)d_in[19];

  const size_t SZ_COMB   = (size_t)BATCH * TLEN * HID * 2;   // 25,165,824 (bf16)
  const size_t SZ_FARM_H = (size_t)8 * TLEN * 32 * 8 * 2;    // 2,097,152 (hoist)
  const size_t SZ_FARM_F = (size_t)4 * TLEN * 32 * 8 * 2;    // 1,048,576 (fb)
  const size_t SZ_F64    = (size_t)16 * TLEN * 16 * 64 * 2;  // 16,777,216
  const size_t SZ_F48    = (size_t)8 * TLEN * 16 * 48 * 2;   // 6,291,456
  const size_t SZ_PRE    = (size_t)16 * TLEN * 2048 * 2;     // 33,554,432
  const size_t NEED_FULL = SZ_COMB + 2 * SZ_FARM_H + 2 * SZ_F64 + 2 * SZ_PRE +
                           2 * 32768 + 2 * 32768 + 2 * 16384; // ~130.2 MB
  bool hoist = ws_size >= NEED_FULL;

  char* p = (char*)d_ws;
  unsigned short* combined = (unsigned short*)p; p += SZ_COMB;
  unsigned short *fAR, *fAL;
  unsigned short *fHR, *fHL, *preR = nullptr, *preL = nullptr;
  unsigned short *btA_r, *btA_l, *btH_r = nullptr, *btH_l = nullptr, *btArm_r, *btArm_l;
  if (hoist) {
    fAR = (unsigned short*)p; p += SZ_FARM_H;
    fAL = (unsigned short*)p; p += SZ_FARM_H;
    fHR = (unsigned short*)p; p += SZ_F64;
    fHL = (unsigned short*)p; p += SZ_F64;
    preR = (unsigned short*)p; p += SZ_PRE;
    preL = (unsigned short*)p; p += SZ_PRE;
    btA_r = (unsigned short*)p; p += 32768;
    btA_l = (unsigned short*)p; p += 32768;
    btH_r = (unsigned short*)p; p += 32768;
    btH_l = (unsigned short*)p; p += 32768;
  } else {
    fAR = (unsigned short*)p; p += SZ_FARM_F;
    fAL = (unsigned short*)p; p += SZ_FARM_F;
    fHR = (unsigned short*)p; p += SZ_F48;
    fHL = (unsigned short*)p; p += SZ_F48;
    btA_r = (unsigned short*)p; p += 65536;
    btA_l = (unsigned short*)p; p += 65536;
    btH_r = btA_r; btH_l = btA_l;  // unused in fb
  }
  btArm_r = (unsigned short*)p; p += 16384;
  btArm_l = (unsigned short*)p;

  prep_kernel<<<dim3((BATCH * TLEN + 255) / 256), 256, 0, stream>>>(
      x, fHR, fHL, fAR, fAL, hoist ? 1 : 0);
  pack_kernel<<<dim3(6), 256, 0, stream>>>(
      hoist ? 1 : 0,
      wih_rh, whh_rh, wih_ra, whh_ra, wih_lh, whh_lh, wih_la, whh_la,
      btA_r, btA_l, btH_r, btH_l, btArm_r, btArm_l);
  if (hoist) {
    pregemm_kernel<<<dim3(512), 256, 0, stream>>>(
        fHR, fHL, btA_r, btA_l, bih_rh, bhh_rh, bih_lh, bhh_lh, preR, preL);
    lstm_hoist<<<dim3(48), 256, 0, stream>>>(
        fAR, fAL, btH_r, btH_l, btArm_r, btArm_l, preR, preL,
        bih_ra, bhh_ra, bih_la, bhh_la, combined);
  } else {
    lstm_fb<<<dim3(24), 256, 0, stream>>>(
        fHR, fHL, fAR, fAL, btA_r, btA_l, btArm_r, btArm_l,
        bih_rh, bhh_rh, bih_ra, bhh_ra, bih_lh, bhh_lh, bih_la, bhh_la, combined);
  }
  attn_kernel<<<dim3(BATCH), 512, 0, stream>>>(combined, att_w, fc_w, fc_b, (float*)d_out);
}

// Round 3
// 430.302 us; speedup vs baseline: 1.2834x; 1.0197x over previous
//
#include <hip/hip_runtime.h>
#include <math.h>

#define BATCH 128
#define TLEN 512
#define XF 266
#define HID 192
#define NC 250

typedef __attribute__((ext_vector_type(8))) short short8;
typedef __attribute__((ext_vector_type(4))) float float4v;

#define NL2E  -1.4426950408889634f
#define NL2E2 -2.8853900817779268f

// fp32 -> bf16 (RNE)
__device__ __forceinline__ unsigned short f2bf(float f) {
  unsigned u = __float_as_uint(f);
  u += 0x7FFF + ((u >> 16) & 1);
  return (unsigned short)(u >> 16);
}
__device__ __forceinline__ float bf2f(unsigned short s) {
  return __uint_as_float(((unsigned)s) << 16);
}

// single-instruction exp2 (v_exp_f32)
__device__ __forceinline__ float exp2i(float x) {
#if __has_builtin(__builtin_amdgcn_exp2f)
  return __builtin_amdgcn_exp2f(x);
#else
  float r;
  asm("v_exp_f32 %0, %1" : "=v"(r) : "v"(x));
  return r;
#endif
}

// LDS-only barrier: does NOT drain vmcnt.
__device__ __forceinline__ void lds_barrier() {
  asm volatile("s_waitcnt lgkmcnt(0)\n\ts_barrier" ::: "memory");
}

// ---------------- K1: feature prep --------------------------------------
// hoist: hands [tile16][t][m16][64], b -> tile b>>3, v=b&7, row (v>>1)*4+(v&1)
//        arms  [tile8][t][m32][8],  b -> tile b>>4, va=b&15,
//                row (va>>3)*16 + ((va&7)>>1)*4 + (va&1)
// fb: hands [tile8][t][m16][48] row=b&15; arms [tile4][t][m32][8] row=b&31

__device__ __forceinline__ void norm_hand(const float* __restrict__ xp,
                                          unsigned short* __restrict__ fp,
                                          int p0, int refp, int hs) {
  float rx = xp[2 * refp], ry = xp[2 * refp + 1];
  float px[21], py[21];
  float minx = 1e30f, maxx = -1e30f, miny = 1e30f, maxy = -1e30f;
#pragma unroll
  for (int i = 0; i < 21; ++i) {
    float ax = xp[2 * (p0 + i)] - rx;
    float ay = xp[2 * (p0 + i) + 1] - ry;
    px[i] = ax; py[i] = ay;
    minx = fminf(minx, ax); maxx = fmaxf(maxx, ax);
    miny = fminf(miny, ay); maxy = fmaxf(maxy, ay);
  }
  float s = fmaxf(maxx - minx, maxy - miny);
  if (s == 0.f) s = 1.f;
  float inv = 1.f / s;
#pragma unroll
  for (int i = 0; i < 21; ++i) {
    fp[2 * i] = f2bf(px[i] * inv);
    fp[2 * i + 1] = f2bf(py[i] * inv);
  }
  for (int i = 42; i < hs; ++i) fp[i] = 0;
}

__device__ __forceinline__ void norm_arm(const float* __restrict__ xp,
                                         unsigned short* __restrict__ fp,
                                         int a, int b, int c) {
  float rx = xp[0], ry = xp[1];
  float x0 = xp[2 * a] - rx, y0 = xp[2 * a + 1] - ry;
  float x1 = xp[2 * b] - rx, y1 = xp[2 * b + 1] - ry;
  float x2 = xp[2 * c] - rx, y2 = xp[2 * c + 1] - ry;
  float w = fmaxf(fmaxf(x0, x1), x2) - fminf(fminf(x0, x1), x2);
  float h = fmaxf(fmaxf(y0, y1), y2) - fminf(fminf(y0, y1), y2);
  float s = fmaxf(w, h);
  if (s == 0.f) s = 1.f;
  float inv = 1.f / s;
  fp[0] = f2bf(x0 * inv); fp[1] = f2bf(y0 * inv);
  fp[2] = f2bf(x1 * inv); fp[3] = f2bf(y1 * inv);
  fp[4] = f2bf(x2 * inv); fp[5] = f2bf(y2 * inv);
  fp[6] = 0; fp[7] = 0;
}

__global__ __launch_bounds__(256) void prep_kernel(
    const float* __restrict__ x,
    unsigned short* __restrict__ fHR, unsigned short* __restrict__ fHL,
    unsigned short* __restrict__ fAR, unsigned short* __restrict__ fAL,
    int mode) {
  int idx = blockIdx.x * 256 + threadIdx.x;
  if (idx >= BATCH * TLEN) return;
  int b = idx >> 9, t = idx & 511;
  const float* xp = x + (size_t)idx * XF;
  size_t hoff, aoff;
  int hs;
  if (mode) {
    hs = 64;
    int vh = b & 7;
    int rowh = (vh >> 1) * 4 + (vh & 1);
    hoff = (((size_t)(b >> 3) * TLEN + t) * 16 + rowh) * 64;
    int va = b & 15;
    int rowa = (va >> 3) * 16 + ((va & 7) >> 1) * 4 + (va & 1);
    aoff = (((size_t)(b >> 4) * TLEN + t) * 32 + rowa) * 8;
  } else {
    hs = 48;
    hoff = (((size_t)(b >> 4) * TLEN + t) * 16 + (b & 15)) * 48;
    aoff = (((size_t)(b >> 5) * TLEN + t) * 32 + (b & 31)) * 8;
  }
  norm_hand(xp, fHR + hoff, 112, 10, hs);  // right hand, ref pt 10
  norm_hand(xp, fHL + hoff, 91, 9, hs);    // left hand, ref pt 9
  norm_arm (xp, fAR + aoff, 6, 8, 10);     // right arm
  norm_arm (xp, fAL + aoff, 5, 7, 9);      // left arm
}

// ---------------- K1b: weight packing (FB MODE ONLY) ----------------------

__global__ __launch_bounds__(256) void pack_kernel(
    const float* __restrict__ wi_rh, const float* __restrict__ wh_rh,
    const float* __restrict__ wi_ra, const float* __restrict__ wh_ra,
    const float* __restrict__ wi_lh, const float* __restrict__ wh_lh,
    const float* __restrict__ wi_la, const float* __restrict__ wh_la,
    unsigned short* __restrict__ btA_r, unsigned short* __restrict__ btA_l,
    unsigned short* __restrict__ btArm_r, unsigned short* __restrict__ btArm_l) {
  int blk = blockIdx.x, tid = threadIdx.x;
  if (blk < 2) {
    const float* wi = blk ? wi_lh : wi_rh;
    const float* wh = blk ? wh_lh : wh_rh;
    unsigned short* dst = blk ? btA_l : btA_r;
    for (int i = tid; i < 256 * 128; i += 256) {
      int g = i >> 7, k = i & 127;
      float s = ((g >> 6) == 2) ? NL2E2 : NL2E;
      float v = (k < 42) ? wi[g * 42 + k] : (k < 64 ? 0.f : wh[g * 64 + (k - 64)]);
      dst[i] = f2bf(v * s);
    }
  } else {
    const float* wi = (blk == 3) ? wi_la : wi_ra;
    const float* wh = (blk == 3) ? wh_la : wh_ra;
    unsigned short* dst = (blk == 3) ? btArm_l : btArm_r;
    for (int i = tid; i < 128 * 64; i += 256) {
      int g = i >> 6, k = i & 63;
      float s = ((g >> 5) == 2) ? NL2E2 : NL2E;
      float v = (k < 6) ? wi[g * 6 + k] : (k < 32 ? 0.f : wh[g * 32 + (k - 32)]);
      dst[i] = f2bf(v * s);
    }
  }
}

// ---------------- K1c: input-projection pre-GEMM (hoist mode) ------------
// Inline f32->bf16 weight conversion (no pack dependency).
// Output split by accumulator row r into TWO sibling instance streams:
//   instance = tile*2 + r  handles batches tile*8 + 2*quad + r.
// Layout per (inst,t): 512 shorts = [jt4][n16][quad4][q4]:
//   off = jt*256 + n*16 + quad*4 + q   (consumer lane reads uint2 = 4 gates)

__global__ __launch_bounds__(256, 1) void pregemm_kernel(
    const unsigned short* __restrict__ f64R, const unsigned short* __restrict__ f64L,
    const float* __restrict__ wiR, const float* __restrict__ wiL,
    const float* __restrict__ biR, const float* __restrict__ bhR,
    const float* __restrict__ biL, const float* __restrict__ bhL,
    unsigned short* __restrict__ preR, unsigned short* __restrict__ preL) {
  int bx = blockIdx.x;
  int lr = bx >> 8, tile = (bx >> 4) & 15, tc = bx & 15;
  const unsigned short* f64 = lr ? f64L : f64R;
  const float* wi = lr ? wiL : wiR;
  const float* bi = lr ? biL : biR;
  const float* bh = lr ? bhL : bhR;
  unsigned short* pre = lr ? preL : preR;
  int tid = threadIdx.x, lane = tid & 63;
  int q = tid >> 6, n = lane & 15, quad = lane >> 4;
  float sq = (q == 2) ? NL2E2 : NL2E;

  short8 Vb[4][2];
  float bias[4];
#pragma unroll
  for (int jg = 0; jg < 4; ++jg) {
    int g = q * 64 + jg * 16 + n;
    bias[jg] = (bi[g] + bh[g]) * sq;
#pragma unroll
    for (int c = 0; c < 2; ++c) {
      short8 vb;
#pragma unroll
      for (int s = 0; s < 8; ++s) {
        int k = c * 32 + quad * 8 + s;
        vb[s] = (short)f2bf(k < 42 ? wi[g * 42 + k] * sq : 0.f);
      }
      Vb[jg][c] = vb;
    }
  }

  for (int i = 0; i < 32; ++i) {
    int t = tc * 32 + i;
    const unsigned short* ap = f64 + ((size_t)(tile * 512 + t) * 16 + n) * 64 + quad * 8;
    short8 Va0 = *(const short8*)ap;
    short8 Va1 = *(const short8*)(ap + 32);
    unsigned short* pb0 = pre + ((size_t)(tile * 2) * 512 + t) * 1024 + n * 16 + quad * 4 + q;
    unsigned short* pb1 = pb0 + (size_t)512 * 1024;
#pragma unroll
    for (int jg = 0; jg < 4; ++jg) {
      float4v acc = {bias[jg], bias[jg], bias[jg], bias[jg]};
      acc = __builtin_amdgcn_mfma_f32_16x16x32_bf16(Va0, Vb[jg][0], acc, 0, 0, 0);
      acc = __builtin_amdgcn_mfma_f32_16x16x32_bf16(Va1, Vb[jg][1], acc, 0, 0, 0);
      pb0[jg * 256] = f2bf(acc[0]);   // row quad*4+0 -> instance 2*tile
      pb1[jg * 256] = f2bf(acc[1]);   // row quad*4+1 -> instance 2*tile+1
    }
  }
}

// ---------------- K2 (hoist): RV=1 MFMA LSTM recurrence -------------------
// One cell per lane per step. Sibling blocks (RSEL=0/1) share feature tiles.
// combined written directly from the activation register (no LDS flush).
// Inline f32 weight conversion; t-loop unrolled x2, static prefetch regs.

template <int H, int CH, int STR, int MB, int SCH, int HOFF, bool HOIST, int RSEL>
__device__ __forceinline__ void lstm_core1(
    unsigned short* __restrict__ Ab0, unsigned short* __restrict__ Ab1,
    const float* __restrict__ wq,   // hands: whh (4H x H); arms: whh (4H x H)
    const float* __restrict__ wx,   // arms: wih (4H x 6); hands unused
    const float* __restrict__ bi, const float* __restrict__ bh,  // arms only
    const unsigned short* __restrict__ featp,   // arms (tile base)
    const unsigned short* __restrict__ prep_,   // hands (instance base)
    unsigned short* __restrict__ combbase,      // combined + col offset
    int b0, int mrow0, int j0) {
  constexpr int XSH = MB * SCH * 8;
  int tid = threadIdx.x;
  int lane = tid & 63, n = lane & 15, quad = lane >> 4;

  // B fragments inline-converted from f32 (pre-scaled by -log2e / -2log2e)
  short8 Vb[4][CH];
  float bias[4];
#pragma unroll
  for (int q = 0; q < 4; ++q) {
    float sq = (q == 2) ? NL2E2 : NL2E;
    int g = q * H + j0 + n;
    if (!HOIST) bias[q] = (bi[g] + bh[g]) * sq;
#pragma unroll
    for (int c = 0; c < CH; ++c) {
      short8 vb;
#pragma unroll
      for (int s = 0; s < 8; ++s) {
        int k = c * 32 + quad * 8 + s;
        float v;
        if (HOIST) {
          v = wq[(size_t)g * H + k];                       // K == H (h-only)
        } else {
          v = (k < 6) ? wx[g * 6 + k]
                      : (k >= 32 ? wq[g * 32 + (k - 32)] : 0.f);
        }
        vb[s] = (short)f2bf(v * sq);
      }
      Vb[q][c] = vb;
    }
  }

  for (int i = tid; i < MB * STR; i += 256) { Ab0[i] = 0; Ab1[i] = 0; }
  __syncthreads();  // zero-init visible before staging writes

  // x staging (arms): static even/odd regs
  bool st = false;
  unsigned short *xd0 = nullptr, *xd1 = nullptr;
  const unsigned short* fp = nullptr;
  short8 xE, xO;
  if (!HOIST) {
    st = tid < MB * SCH;
    xd0 = Ab0 + tid * STR;
    xd1 = Ab1 + tid * STR;
    fp = featp + tid * 8;
    if (st) {
      *(short8*)xd0 = *(const short8*)fp;            // feat[0] -> buf0
      xO = *(const short8*)(fp + XSH);               // feat[1]
      xE = *(const short8*)(fp + 2 * (size_t)XSH);   // feat[2]
    }
    fp += 3 * (size_t)XSH;
  }

  // packed-pre prefetch (hands): uint2 per step, static even/odd regs
  const unsigned short *ppE = nullptr, *ppO = nullptr;
  uint2 pE = {0, 0}, pO = {0, 0};
  if (HOIST) {
    const unsigned short* pp0 = prep_ + (size_t)(j0 >> 4) * 256 + n * 16 + quad * 4;
    pE = *(const uint2*)pp0;              // pre[0]
    pO = *(const uint2*)(pp0 + 1024);     // pre[1]
    ppE = pp0 + 2 * 1024;
    ppO = pp0 + 3 * 1024;
  }

  float cc = 0.f;
  __syncthreads();

  const unsigned short* ard0 = Ab0 + (mrow0 + n) * STR;
  const unsigned short* ard1 = Ab1 + (mrow0 + n) * STR;
  unsigned short* hw0 = Ab0 + (mrow0 + quad * 4 + RSEL) * STR + HOFF + j0 + n;
  unsigned short* hw1 = Ab1 + (mrow0 + quad * 4 + RSEL) * STR + HOFF + j0 + n;
  unsigned short* cgp = combbase +
      ((size_t)(b0 + (mrow0 >> 1) + quad * 2) * TLEN) * HID + j0 + n;

  for (int tt = 0; tt < TLEN; tt += 2) {
    // ------- even step t = tt (reads buf0, writes h to buf1) -------------
    {
      const int t = tt;
      short8 Va[CH];
#pragma unroll
      for (int c = 0; c < CH; ++c)
        Va[c] = *(const short8*)(ard0 + c * 32 + quad * 8);

      float4v acc[4];
#pragma unroll
      for (int q = 0; q < 4; ++q) acc[q] = (float4v){0.f, 0.f, 0.f, 0.f};
      if (HOIST) {
        acc[0][RSEL] = __uint_as_float(pE.x << 16);
        acc[1][RSEL] = __uint_as_float(pE.x & 0xffff0000u);
        acc[2][RSEL] = __uint_as_float(pE.y << 16);
        acc[3][RSEL] = __uint_as_float(pE.y & 0xffff0000u);
        if (t + 2 < TLEN) pE = *(const uint2*)ppE;   // refill (pre[t+2])
        ppE += 2 * 1024;
      } else {
#pragma unroll
        for (int q = 0; q < 4; ++q) acc[q][RSEL] = bias[q];
      }
#pragma unroll
      for (int q = 0; q < 4; ++q)
#pragma unroll
        for (int c = 0; c < CH; ++c)
          acc[q] = __builtin_amdgcn_mfma_f32_16x16x32_bf16(Va[c], Vb[q][c], acc[q], 0, 0, 0);

      if (!HOIST) {
        if (st) {
          *(short8*)xd1 = xO;                          // feat[t+1] -> buf1
          if (t + 3 < TLEN) xO = *(const short8*)fp;   // feat[t+3]
        }
        fp += XSH;
      }

      float Ei = exp2i(acc[0][RSEL]);
      float Ef = exp2i(acc[1][RSEL]);
      float Eg = exp2i(acc[2][RSEL]);
      float Eo = exp2i(acc[3][RSEL]);
      float gf = __builtin_amdgcn_rcpf(1.f + Ef);
      float ig = (1.f - Eg) * __builtin_amdgcn_rcpf((1.f + Ei) * (1.f + Eg));
      float cv = fmaf(gf, cc, ig);
      cc = cv;
      float Ec = exp2i(cv * NL2E2);
      float hv = (1.f - Ec) * __builtin_amdgcn_rcpf((1.f + Eo) * (1.f + Ec));
      unsigned short hb = f2bf(hv);
      hw1[0] = hb;        // LDS for recurrence
      *cgp = hb;          // direct global store of combined
      cgp += HID;
      lds_barrier();
    }
    // ------- odd step t = tt+1 (reads buf1, writes h to buf0) ------------
    {
      const int t = tt + 1;
      short8 Va[CH];
#pragma unroll
      for (int c = 0; c < CH; ++c)
        Va[c] = *(const short8*)(ard1 + c * 32 + quad * 8);

      float4v acc[4];
#pragma unroll
      for (int q = 0; q < 4; ++q) acc[q] = (float4v){0.f, 0.f, 0.f, 0.f};
      if (HOIST) {
        acc[0][RSEL] = __uint_as_float(pO.x << 16);
        acc[1][RSEL] = __uint_as_float(pO.x & 0xffff0000u);
        acc[2][RSEL] = __uint_as_float(pO.y << 16);
        acc[3][RSEL] = __uint_as_float(pO.y & 0xffff0000u);
        if (t + 2 < TLEN) pO = *(const uint2*)ppO;   // refill (pre[t+2])
        ppO += 2 * 1024;
      } else {
#pragma unroll
        for (int q = 0; q < 4; ++q) acc[q][RSEL] = bias[q];
      }
#pragma unroll
      for (int q = 0; q < 4; ++q)
#pragma unroll
        for (int c = 0; c < CH; ++c)
          acc[q] = __builtin_amdgcn_mfma_f32_16x16x32_bf16(Va[c], Vb[q][c], acc[q], 0, 0, 0);

      if (!HOIST) {
        if (st) {
          if (t + 1 < TLEN) *(short8*)xd0 = xE;        // feat[t+1] -> buf0
          if (t + 3 < TLEN) xE = *(const short8*)fp;   // feat[t+3]
        }
        fp += XSH;
      }

      float Ei = exp2i(acc[0][RSEL]);
      float Ef = exp2i(acc[1][RSEL]);
      float Eg = exp2i(acc[2][RSEL]);
      float Eo = exp2i(acc[3][RSEL]);
      float gf = __builtin_amdgcn_rcpf(1.f + Ef);
      float ig = (1.f - Eg) * __builtin_amdgcn_rcpf((1.f + Ei) * (1.f + Eg));
      float cv = fmaf(gf, cc, ig);
      cc = cv;
      float Ec = exp2i(cv * NL2E2);
      float hv = (1.f - Ec) * __builtin_amdgcn_rcpf((1.f + Eo) * (1.f + Ec));
      unsigned short hb = f2bf(hv);
      hw0[0] = hb;
      *cgp = hb;
      cgp += HID;
      lds_barrier();
    }
  }
}

__global__ __launch_bounds__(256, 1) void lstm_hoist(
    const unsigned short* __restrict__ fAR, const unsigned short* __restrict__ fAL,
    const float* __restrict__ whh_rh, const float* __restrict__ whh_lh,
    const float* __restrict__ wih_ra, const float* __restrict__ whh_ra,
    const float* __restrict__ wih_la, const float* __restrict__ whh_la,
    const unsigned short* __restrict__ preR, const unsigned short* __restrict__ preL,
    const float* __restrict__ b1i, const float* __restrict__ b1h,
    const float* __restrict__ b3i, const float* __restrict__ b3h,
    unsigned short* __restrict__ combined) {
  __shared__ __align__(16) unsigned short A0[2304];
  __shared__ __align__(16) unsigned short A1[2304];
  int blk = blockIdx.x;
  int wave = threadIdx.x >> 6;
  if (blk < 64) {           // hands: 16 tiles x 2 r-instances x 2 sides
    int lr = blk >> 5, rem = blk & 31, tl = rem >> 1, r = rem & 1;
    const unsigned short* pp = (lr ? preL : preR) + (size_t)rem * 512 * 1024;
    const float* wq = lr ? whh_lh : whh_rh;
    unsigned short* cmb = combined + (lr ? 96 : 0);
    if (r == 0)
      lstm_core1<64, 2, 72, 16, 0, 0, true, 0>(
          A0, A1, wq, nullptr, nullptr, nullptr, nullptr, pp, cmb,
          tl * 8 + 0, 0, wave * 16);
    else
      lstm_core1<64, 2, 72, 16, 0, 0, true, 1>(
          A0, A1, wq, nullptr, nullptr, nullptr, nullptr, pp, cmb,
          tl * 8 + 1, 0, wave * 16);
  } else {                  // arms: 8 tiles x 2 r-instances x 2 sides
    int a = blk - 64;
    int la = a >> 4, rem = a & 15, tl = rem >> 1, r = rem & 1;
    const unsigned short* fpz = (la ? fAL : fAR) + (size_t)tl * 512 * 256;
    const float* wxp = la ? wih_la : wih_ra;
    const float* wqp = la ? whh_la : whh_ra;
    const float* bip = la ? b3i : b1i;
    const float* bhp = la ? b3h : b1h;
    unsigned short* cmb = combined + (la ? 160 : 64);
    int mrow0 = (wave >> 1) * 16, j0 = (wave & 1) * 16;
    if (r == 0)
      lstm_core1<32, 2, 72, 32, 1, 32, false, 0>(
          A0, A1, wqp, wxp, bip, bhp, fpz, nullptr, cmb,
          tl * 16 + 0, mrow0, j0);
    else
      lstm_core1<32, 2, 72, 32, 1, 32, false, 1>(
          A0, A1, wqp, wxp, bip, bhp, fpz, nullptr, cmb,
          tl * 16 + 1, mrow0, j0);
  }
}

// ---------------- K2 (fallback): round-2 RV=4 core ------------------------

template <int H, int CH, int STR, int MB, int SCH, int HOFF, int RV>
__device__ __forceinline__ void lstm_core_fb(
    unsigned short* __restrict__ Ab0, unsigned short* __restrict__ Ab1,
    const unsigned short* __restrict__ Bt,
    const float* __restrict__ bi, const float* __restrict__ bh,
    const unsigned short* __restrict__ featp,
    unsigned short* __restrict__ combbase,
    int b0, int mrow0, int j0) {
  constexpr int K = CH * 32;
  constexpr int XSH = MB * SCH * 8;
  constexpr int JQ = H / 4;
  constexpr int VR = MB;
  int tid = threadIdx.x;
  int lane = tid & 63, n = lane & 15, quad = lane >> 4;

  short8 Vb[4][CH];
  float bias[4];
#pragma unroll
  for (int q = 0; q < 4; ++q) {
    int g = q * H + j0 + n;
    bias[q] = (bi[g] + bh[g]) * ((q == 2) ? NL2E2 : NL2E);
#pragma unroll
    for (int c = 0; c < CH; ++c)
      Vb[q][c] = *(const short8*)(Bt + (size_t)g * K + c * 32 + quad * 8);
  }

  for (int i = tid; i < MB * STR; i += 256) { Ab0[i] = 0; Ab1[i] = 0; }
  __syncthreads();

  bool st = tid < MB * SCH;
  int sm = SCH ? tid / SCH : 0, sc8 = SCH ? tid % SCH : 0;
  unsigned short* xd0 = Ab0 + sm * STR + sc8 * 8;
  unsigned short* xd1 = Ab1 + sm * STR + sc8 * 8;
  const unsigned short* fp = featp + tid * 8;
  short8 xE, xO;
  if (st) {
    *(short8*)xd0 = *(const short8*)fp;
    xO = *(const short8*)(fp + XSH);
    xE = *(const short8*)(fp + 2 * (size_t)XSH);
  }
  fp += 3 * (size_t)XSH;

  float4v cc = {0.f, 0.f, 0.f, 0.f};
  __syncthreads();

  const unsigned short* ard0 = Ab0 + (mrow0 + n) * STR;
  const unsigned short* ard1 = Ab1 + (mrow0 + n) * STR;
  unsigned short* hw0 = Ab0 + (mrow0 + quad * 4) * STR + HOFF + j0 + n;
  unsigned short* hw1 = Ab1 + (mrow0 + quad * 4) * STR + HOFF + j0 + n;

  int vi = tid / JQ, fjq = tid % JQ;
  bool fon = tid < VR * JQ;
  int fm = vi;
  const unsigned short* fl0 = Ab0 + fm * STR + HOFF + fjq * 4;
  const unsigned short* fl1 = Ab1 + fm * STR + HOFF + fjq * 4;
  unsigned short* cfp = combbase + ((size_t)(b0 + vi) * TLEN) * HID + fjq * 4;

#define ACT_FB(hw)                                                            \
  _Pragma("unroll")                                                           \
  for (int r = 0; r < RV; ++r) {                                              \
    float Ei = exp2i(acc[0][r]);                                              \
    float Ef = exp2i(acc[1][r]);                                              \
    float Eg = exp2i(acc[2][r]);                                              \
    float Eo = exp2i(acc[3][r]);                                              \
    float gf = __builtin_amdgcn_rcpf(1.f + Ef);                               \
    float ig = (1.f - Eg) * __builtin_amdgcn_rcpf((1.f + Ei) * (1.f + Eg));   \
    float cv = fmaf(gf, cc[r], ig);                                           \
    cc[r] = cv;                                                               \
    float Ec = exp2i(cv * NL2E2);                                             \
    float hv = (1.f - Ec) * __builtin_amdgcn_rcpf((1.f + Eo) * (1.f + Ec));   \
    (hw)[r * STR] = f2bf(hv);                                                 \
  }

  for (int tt = 0; tt < TLEN; tt += 2) {
    {
      const int t = tt;
      if (fon && t > 0) {
        *(uint2*)cfp = *(const uint2*)fl0;
        cfp += HID;
      }
      short8 Va[CH];
#pragma unroll
      for (int c = 0; c < CH; ++c)
        Va[c] = *(const short8*)(ard0 + c * 32 + quad * 8);
      float4v acc[4];
#pragma unroll
      for (int q = 0; q < 4; ++q)
        acc[q] = (float4v){bias[q], bias[q], bias[q], bias[q]};
#pragma unroll
      for (int q = 0; q < 4; ++q)
#pragma unroll
        for (int c = 0; c < CH; ++c)
          acc[q] = __builtin_amdgcn_mfma_f32_16x16x32_bf16(Va[c], Vb[q][c], acc[q], 0, 0, 0);
      if (st) {
        *(short8*)xd1 = xO;
        if (t + 3 < TLEN) xO = *(const short8*)fp;
      }
      fp += XSH;
      ACT_FB(hw1)
      lds_barrier();
    }
    {
      const int t = tt + 1;
      if (fon) {
        *(uint2*)cfp = *(const uint2*)fl1;
        cfp += HID;
      }
      short8 Va[CH];
#pragma unroll
      for (int c = 0; c < CH; ++c)
        Va[c] = *(const short8*)(ard1 + c * 32 + quad * 8);
      float4v acc[4];
#pragma unroll
      for (int q = 0; q < 4; ++q)
        acc[q] = (float4v){bias[q], bias[q], bias[q], bias[q]};
#pragma unroll
      for (int q = 0; q < 4; ++q)
#pragma unroll
        for (int c = 0; c < CH; ++c)
          acc[q] = __builtin_amdgcn_mfma_f32_16x16x32_bf16(Va[c], Vb[q][c], acc[q], 0, 0, 0);
      if (st) {
        if (t + 1 < TLEN) *(short8*)xd0 = xE;
        if (t + 3 < TLEN) xE = *(const short8*)fp;
      }
      fp += XSH;
      ACT_FB(hw0)
      lds_barrier();
    }
  }
  if (fon) *(uint2*)cfp = *(const uint2*)fl0;
#undef ACT_FB
}

__global__ __launch_bounds__(256, 1) void lstm_fb(
    const unsigned short* __restrict__ fHR, const unsigned short* __restrict__ fHL,
    const unsigned short* __restrict__ fAR, const unsigned short* __restrict__ fAL,
    const unsigned short* __restrict__ btA_r, const unsigned short* __restrict__ btA_l,
    const unsigned short* __restrict__ btArm_r, const unsigned short* __restrict__ btArm_l,
    const float* __restrict__ b0i, const float* __restrict__ b0h,
    const float* __restrict__ b1i, const float* __restrict__ b1h,
    const float* __restrict__ b2i, const float* __restrict__ b2h,
    const float* __restrict__ b3i, const float* __restrict__ b3h,
    unsigned short* __restrict__ combined) {
  __shared__ __align__(16) unsigned short A0[2304];
  __shared__ __align__(16) unsigned short A1[2304];
  int blk = blockIdx.x;
  int wave = threadIdx.x >> 6;
  if (blk < 16) {
    int lr = blk >> 3, tl = blk & 7;
    lstm_core_fb<64, 4, 136, 16, 6, 64, 4>(
        A0, A1, lr ? btA_l : btA_r, lr ? b2i : b0i, lr ? b2h : b0h,
        (lr ? fHL : fHR) + (size_t)tl * 512 * 768,
        combined + (lr ? 96 : 0), tl * 16, 0, wave * 16);
  } else {
    int a = blk - 16;
    int la = a >> 2, tl = a & 3;
    lstm_core_fb<32, 2, 72, 32, 1, 32, 4>(
        A0, A1, la ? btArm_l : btArm_r, la ? b3i : b1i, la ? b3h : b1h,
        (la ? fAL : fAR) + (size_t)tl * 512 * 256,
        combined + (la ? 160 : 64), tl * 32, (wave >> 1) * 16, (wave & 1) * 16);
  }
}

// ---------------- K3: attention + FC (512 threads, bf16 combined) ---------

__global__ __launch_bounds__(512) void attn_kernel(const unsigned short* __restrict__ combined,
                                                   const float* __restrict__ att_w,
                                                   const float* __restrict__ fc_w,
                                                   const float* __restrict__ fc_b,
                                                   float* __restrict__ dout) {
  __shared__ float sc[TLEN];
  __shared__ float aw[HID];
  __shared__ float pctx[8][HID];
  __shared__ float ctx[HID];
  __shared__ float red[8];
  int b = blockIdx.x, tid = threadIdx.x;
  int lane = tid & 63, wave = tid >> 6;
  const unsigned short* cb = combined + (size_t)b * TLEN * HID;
  if (tid < HID) aw[tid] = att_w[tid];
  __syncthreads();
  float a0 = aw[lane], a1 = aw[lane + 64], a2 = aw[lane + 128];

  int t0 = wave * 64;
  for (int t = t0; t < t0 + 64; t += 2) {
    const unsigned short* r0 = cb + (size_t)t * HID;
    const unsigned short* r1 = r0 + HID;
    float p0 = a0 * bf2f(r0[lane]) + a1 * bf2f(r0[lane + 64]) + a2 * bf2f(r0[lane + 128]);
    float p1 = a0 * bf2f(r1[lane]) + a1 * bf2f(r1[lane + 64]) + a2 * bf2f(r1[lane + 128]);
#pragma unroll
    for (int o = 32; o; o >>= 1) {
      p0 += __shfl_xor(p0, o, 64);
      p1 += __shfl_xor(p1, o, 64);
    }
    if (lane == 0) { sc[t] = p0; sc[t + 1] = p1; }
  }
  __syncthreads();

  float e = sc[tid];
  float lmax = e;
#pragma unroll
  for (int o = 32; o; o >>= 1) lmax = fmaxf(lmax, __shfl_xor(lmax, o, 64));
  if (lane == 0) red[wave] = lmax;
  __syncthreads();
  float m = red[0];
#pragma unroll
  for (int w = 1; w < 8; ++w) m = fmaxf(m, red[w]);
  __syncthreads();
  float ex = __expf(e - m);
  float ls = ex;
#pragma unroll
  for (int o = 32; o; o >>= 1) ls += __shfl_xor(ls, o, 64);
  if (lane == 0) red[wave] = ls;
  __syncthreads();
  float S = red[0];
#pragma unroll
  for (int w = 1; w < 8; ++w) S += red[w];
  float wgt = ex / S;
  sc[tid] = wgt;
  dout[BATCH * NC + b * TLEN + tid] = wgt;  // weights (B,T,1)
  __syncthreads();

#pragma unroll
  for (int p = 0; p < 3; ++p) {
    int h = p * 64 + lane;
    float c0 = 0.f, c1 = 0.f, c2 = 0.f, c3 = 0.f;
    for (int t = t0; t < t0 + 64; t += 4) {
      c0 += sc[t] * bf2f(cb[(size_t)t * HID + h]);
      c1 += sc[t + 1] * bf2f(cb[(size_t)(t + 1) * HID + h]);
      c2 += sc[t + 2] * bf2f(cb[(size_t)(t + 2) * HID + h]);
      c3 += sc[t + 3] * bf2f(cb[(size_t)(t + 3) * HID + h]);
    }
    pctx[wave][h] = (c0 + c1) + (c2 + c3);
  }
  __syncthreads();
  if (tid < HID) {
    float s = pctx[0][tid];
#pragma unroll
    for (int w = 1; w < 8; ++w) s += pctx[w][tid];
    ctx[tid] = s;
  }
  __syncthreads();

  if (tid < NC) {
    const float* wr = fc_w + (size_t)tid * HID;
    float s0 = fc_b[tid], s1 = 0.f, s2 = 0.f, s3 = 0.f;
#pragma unroll
    for (int h = 0; h < HID; h += 4) {
      s0 += ctx[h] * wr[h];
      s1 += ctx[h + 1] * wr[h + 1];
      s2 += ctx[h + 2] * wr[h + 2];
      s3 += ctx[h + 3] * wr[h + 3];
    }
    dout[b * NC + tid] = (s0 + s1) + (s2 + s3);  // logits (B,250)
  }
}

// ---------------- launcher ----------------

extern "C" void kernel_launch(void* const* d_in, const int* in_sizes, int n_in,
                              void* d_out, int out_size, void* d_ws, size_t ws_size,
                              hipStream_t stream) {
  const float* x = (const float*)d_in[0];
  const float* wih_rh = (const float*)d_in[1];
  const float* whh_rh = (const float*)d_in[2];
  const float* bih_rh = (const float*)d_in[3];
  const float* bhh_rh = (const float*)d_in[4];
  const float* wih_ra = (const float*)d_in[5];
  const float* whh_ra = (const float*)d_in[6];
  const float* bih_ra = (const float*)d_in[7];
  const float* bhh_ra = (const float*)d_in[8];
  const float* wih_lh = (const float*)d_in[9];
  const float* whh_lh = (const float*)d_in[10];
  const float* bih_lh = (const float*)d_in[11];
  const float* bhh_lh = (const float*)d_in[12];
  const float* wih_la = (const float*)d_in[13];
  const float* whh_la = (const float*)d_in[14];
  const float* bih_la = (const float*)d_in[15];
  const float* bhh_la = (const float*)d_in[16];
  const float* att_w = (const float*)d_in[17];
  const float* fc_w = (const float*)d_in[18];
  const float* fc_b = (const float*)d_in[19];

  const size_t SZ_COMB   = (size_t)BATCH * TLEN * HID * 2;   // 25,165,824 (bf16)
  const size_t SZ_FARM_H = (size_t)8 * TLEN * 32 * 8 * 2;    // 2,097,152 (hoist)
  const size_t SZ_FARM_F = (size_t)4 * TLEN * 32 * 8 * 2;    // 1,048,576 (fb)
  const size_t SZ_F64    = (size_t)16 * TLEN * 16 * 64 * 2;  // 16,777,216
  const size_t SZ_F48    = (size_t)8 * TLEN * 16 * 48 * 2;   // 6,291,456
  const size_t SZ_PRE    = (size_t)32 * TLEN * 1024 * 2;     // 33,554,432
  const size_t NEED_FULL = SZ_COMB + 2 * SZ_FARM_H + 2 * SZ_F64 + 2 * SZ_PRE;
  bool hoist = ws_size >= NEED_FULL;

  char* p = (char*)d_ws;
  unsigned short* combined = (unsigned short*)p; p += SZ_COMB;
  unsigned short *fAR, *fAL;
  unsigned short *fHR, *fHL, *preR = nullptr, *preL = nullptr;
  unsigned short *btA_r = nullptr, *btA_l = nullptr, *btArm_r = nullptr, *btArm_l = nullptr;
  if (hoist) {
    fAR = (unsigned short*)p; p += SZ_FARM_H;
    fAL = (unsigned short*)p; p += SZ_FARM_H;
    fHR = (unsigned short*)p; p += SZ_F64;
    fHL = (unsigned short*)p; p += SZ_F64;
    preR = (unsigned short*)p; p += SZ_PRE;
    preL = (unsigned short*)p; p += SZ_PRE;
  } else {
    fAR = (unsigned short*)p; p += SZ_FARM_F;
    fAL = (unsigned short*)p; p += SZ_FARM_F;
    fHR = (unsigned short*)p; p += SZ_F48;
    fHL = (unsigned short*)p; p += SZ_F48;
    btA_r = (unsigned short*)p; p += 65536;
    btA_l = (unsigned short*)p; p += 65536;
    btArm_r = (unsigned short*)p; p += 16384;
    btArm_l = (unsigned short*)p;
  }

  prep_kernel<<<dim3((BATCH * TLEN + 255) / 256), 256, 0, stream>>>(
      x, fHR, fHL, fAR, fAL, hoist ? 1 : 0);
  if (hoist) {
    pregemm_kernel<<<dim3(512), 256, 0, stream>>>(
        fHR, fHL, wih_rh, wih_lh, bih_rh, bhh_rh, bih_lh, bhh_lh, preR, preL);
    lstm_hoist<<<dim3(96), 256, 0, stream>>>(
        fAR, fAL, whh_rh, whh_lh, wih_ra, whh_ra, wih_la, whh_la,
        preR, preL, bih_ra, bhh_ra, bih_la, bhh_la, combined);
  } else {
    pack_kernel<<<dim3(4), 256, 0, stream>>>(
        wih_rh, whh_rh, wih_ra, whh_ra, wih_lh, whh_lh, wih_la, whh_la,
        btA_r, btA_l, btArm_r, btArm_l);
    lstm_fb<<<dim3(24), 256, 0, stream>>>(
        fHR, fHL, fAR, fAL, btA_r, btA_l, btArm_r, btArm_l,
        bih_rh, bhh_rh, bih_ra, bhh_ra, bih_lh, bhh_lh, bih_la, bhh_la, combined);
  }
  attn_kernel<<<dim3(BATCH), 512, 0, stream>>>(combined, att_w, fc_w, fc_b, (float*)d_out);
}